// Round 7
// baseline (1910.987 us; speedup 1.0000x reference)
//
#include <hip/hip_runtime.h>
#include <cstdint>
#include <cstddef>

// Problem constants (from reference)
#define NN   50000
#define EE   800000
#define ETOT (EE + NN)      // + self loops
#define HC   256            // H*C
#define NEG_SLOPE 0.2f
#define SENT_WORDS 25000
#define SENT_VAL 0x42C80000u

typedef __attribute__((ext_vector_type(8))) short g4_bf16x8;
typedef __attribute__((ext_vector_type(4))) float g4_f32x4;

// ---- bf16 helpers (raw ushort, explicit RNE) ------------------------------
__device__ __forceinline__ float g4_bf2f(unsigned short h) {
    union { unsigned int u; float f; } v;
    v.u = ((unsigned int)h) << 16;
    return v.f;
}
__device__ __forceinline__ unsigned short g4_f2bf(float f) {
    union { float f; unsigned int u; } v;
    v.f = f;
    unsigned int u = v.u;
    u += 0x7fffu + ((u >> 16) & 1u);   // round-to-nearest-even
    return (unsigned short)(u >> 16);
}
__device__ __forceinline__ float g4_ld(const void* p, size_t i, int isf) {
    return isf ? ((const float*)p)[i] : g4_bf2f(((const unsigned short*)p)[i]);
}
// channel permutation: stored pos p = c*4 + head  (c = within-head channel)
__device__ __forceinline__ int g4_perm(int o)  { return (o & 63) * 4 + (o >> 6); }
__device__ __forceinline__ int g4_operm(int p) { return (p & 3) * 64 + (p >> 2); }
// monotonic float<->uint encoding for atomicMax
__device__ __forceinline__ unsigned int g4_enc(float f) {
    unsigned int u = __float_as_uint(f);
    return (u & 0x80000000u) ? ~u : (u | 0x80000000u);
}
__device__ __forceinline__ float g4_dec(unsigned int e) {
    unsigned int u = (e & 0x80000000u) ? (e ^ 0x80000000u) : ~e;
    return __uint_as_float(u);
}

// ---------------------------------------------------------------------------
// Dtype detection
// ---------------------------------------------------------------------------
__global__ void g4_detect(const unsigned int* __restrict__ xw,
                          const int* __restrict__ ei32, int* __restrict__ flags) {
    __shared__ int cnt[256];
    int t = threadIdx.x;
    unsigned int w = xw[t];
    int e = (int)((w >> 23) & 0xffu);
    cnt[t] = (e >= 110 && e <= 135) ? 1 : 0;
    __syncthreads();
    for (int off = 128; off > 0; off >>= 1) {
        if (t < off) cnt[t] += cnt[t + off];
        __syncthreads();
    }
    if (t == 0) {
        flags[0] = (cnt[0] >= 128) ? 1 : 0;
        int i64 = (ei32[1] == 0 && ei32[3] == 0 && ei32[5] == 0 &&
                   ei32[7] == 0 && ei32[9] == 0) ? 1 : 0;
        flags[1] = i64;
    }
}

// ---------------------------------------------------------------------------
// Zero CSR counters + d_out sentinel
// ---------------------------------------------------------------------------
__global__ void g4_zero(int* __restrict__ deg, int* __restrict__ cnt,
                        unsigned int* __restrict__ outw) {
    int i = blockIdx.x * 256 + threadIdx.x;
    if (i < NN) { deg[i] = 0; cnt[i] = 0; }
    if (i < SENT_WORDS) outw[i] = SENT_VAL;
}
// zero per-layer softmax state (NN*4 entries)
__global__ void g4_zero2(unsigned int* __restrict__ encmax, float* __restrict__ denom) {
    int i = blockIdx.x * 256 + threadIdx.x;
    if (i < NN * 4) { encmax[i] = 0u; denom[i] = 0.f; }
}

// ---------------------------------------------------------------------------
// CSR build
// ---------------------------------------------------------------------------
__global__ void g4_hist(const int* __restrict__ ei, const int* __restrict__ flags,
                        int* __restrict__ deg) {
    int e = blockIdx.x * blockDim.x + threadIdx.x;
    if (e >= ETOT) return;
    int i64 = flags[1];
    int d;
    if (e < EE) d = i64 ? ei[2 * (EE + e)] : ei[EE + e];
    else        d = e - EE;
    atomicAdd(&deg[d], 1);
}

__global__ void g4_scan_block(const int* __restrict__ deg, int* __restrict__ tmp,
                              int* __restrict__ partial) {
    __shared__ int sh[256];
    int i = blockIdx.x * 256 + threadIdx.x;
    int v = (i < NN) ? deg[i] : 0;
    sh[threadIdx.x] = v;
    __syncthreads();
    for (int off = 1; off < 256; off <<= 1) {
        int t = (threadIdx.x >= off) ? sh[threadIdx.x - off] : 0;
        __syncthreads();
        sh[threadIdx.x] += t;
        __syncthreads();
    }
    if (i < NN) tmp[i] = sh[threadIdx.x] - v;
    if (threadIdx.x == 255) partial[blockIdx.x] = sh[255];
}

__global__ void g4_scan_partial(int* __restrict__ partial, int nb,
                                int* __restrict__ rowptrN) {
    __shared__ int sh[256];
    int v = (threadIdx.x < nb) ? partial[threadIdx.x] : 0;
    sh[threadIdx.x] = v;
    __syncthreads();
    for (int off = 1; off < 256; off <<= 1) {
        int t = (threadIdx.x >= off) ? sh[threadIdx.x - off] : 0;
        __syncthreads();
        sh[threadIdx.x] += t;
        __syncthreads();
    }
    if (threadIdx.x < nb) partial[threadIdx.x] = sh[threadIdx.x] - v;
    if (threadIdx.x == 0) *rowptrN = ETOT;
}

__global__ void g4_scan_add(const int* __restrict__ tmp, const int* __restrict__ partial,
                            int* __restrict__ rowptr) {
    int i = blockIdx.x * 256 + threadIdx.x;
    if (i < NN) rowptr[i] = tmp[i] + partial[blockIdx.x];
}

__global__ void g4_fill_csr(const int* __restrict__ ei, const int* __restrict__ flags,
                            const int* __restrict__ rowptr,
                            int* __restrict__ cnt, int* __restrict__ col,
                            int* __restrict__ dstarr) {
    int e = blockIdx.x * blockDim.x + threadIdx.x;
    if (e >= ETOT) return;
    int i64 = flags[1];
    int s, d;
    if (e < EE) {
        s = i64 ? ei[2 * e] : ei[e];
        d = i64 ? ei[2 * (EE + e)] : ei[EE + e];
    } else {
        s = e - EE; d = e - EE;
    }
    int pos = rowptr[d] + atomicAdd(&cnt[d], 1);
    col[pos] = s;
    dstarr[pos] = d;
}

// ---------------------------------------------------------------------------
// MFMA GEMM: C[M,Nc](bf16, channel-permuted cols) = A[M,K] @ B[K,Nc].
// permB: A columns are stored-permuted -> read B row g4_operm(gk).
// ---------------------------------------------------------------------------
#define LDK 40
__global__ __launch_bounds__(256) void g4_gemm_mfma(
    const void* __restrict__ A, int a_mode, const void* __restrict__ B, int permB,
    const int* __restrict__ flags, unsigned short* __restrict__ C,
    int M, int K, int Nc) {
    __shared__ short As[128 * LDK];
    __shared__ short Bs[128 * LDK];
    const int isf = flags[0];
    const int af  = (a_mode == 0) ? isf : 0;
    const int tid  = threadIdx.x;
    const int lane = tid & 63;
    const int wave = tid >> 6;
    const int wr = wave >> 1;
    const int wc = wave & 1;
    const int quad = lane >> 4;
    const int l15  = lane & 15;
    const int bm = blockIdx.x * 128;
    const int bn = blockIdx.y * 128;
    const int a_vec = (af == 0) && ((K & 15) == 0);

    g4_f32x4 acc[4][4];
    #pragma unroll
    for (int it = 0; it < 4; it++)
        #pragma unroll
        for (int jt = 0; jt < 4; jt++) {
            acc[it][jt].x = 0.f; acc[it][jt].y = 0.f;
            acc[it][jt].z = 0.f; acc[it][jt].w = 0.f;
        }

    for (int k0 = 0; k0 < K; k0 += 32) {
        // ---- stage A tile
        {
            int row = tid >> 1;
            int kc  = (tid & 1) * 16;
            int gm  = bm + row;
            short v[16];
            if (a_vec && gm < M && (k0 + kc + 16) <= K) {
                const short* ap = (const short*)A + (size_t)gm * K + k0 + kc;
                *(g4_bf16x8*)&v[0] = *(const g4_bf16x8*)ap;
                *(g4_bf16x8*)&v[8] = *(const g4_bf16x8*)(ap + 8);
            } else {
                #pragma unroll
                for (int j = 0; j < 16; j++) {
                    int gk = k0 + kc + j;
                    if (gm < M && gk < K) {
                        if (af == 0) v[j] = ((const short*)A)[(size_t)gm * K + gk];
                        else         v[j] = (short)g4_f2bf(((const float*)A)[(size_t)gm * K + gk]);
                    } else v[j] = 0;
                }
            }
            short* dst = &As[row * LDK + kc];
            *(g4_bf16x8*)dst       = *(g4_bf16x8*)&v[0];
            *(g4_bf16x8*)(dst + 8) = *(g4_bf16x8*)&v[8];
        }
        // ---- stage B tile transposed: Bs[n][k]; row permuted if permB
        {
            int n  = tid & 127;
            int kc = (tid >> 7) * 16;
            int gn = bn + n;
            short v[16];
            #pragma unroll
            for (int j = 0; j < 16; j++) {
                int gk = k0 + kc + j;
                if (gk < K && gn < Nc) {
                    int row = permB ? g4_operm(gk) : gk;
                    if (isf == 0) v[j] = ((const short*)B)[(size_t)row * Nc + gn];
                    else          v[j] = (short)g4_f2bf(((const float*)B)[(size_t)row * Nc + gn]);
                } else v[j] = 0;
            }
            short* dst = &Bs[n * LDK + kc];
            *(g4_bf16x8*)dst       = *(g4_bf16x8*)&v[0];
            *(g4_bf16x8*)(dst + 8) = *(g4_bf16x8*)&v[8];
        }
        __syncthreads();
        g4_bf16x8 afr[4], bfr[4];
        #pragma unroll
        for (int it = 0; it < 4; it++) {
            int m = wr * 64 + it * 16 + l15;
            afr[it] = *(const g4_bf16x8*)&As[m * LDK + quad * 8];
        }
        #pragma unroll
        for (int jt = 0; jt < 4; jt++) {
            int n = wc * 64 + jt * 16 + l15;
            bfr[jt] = *(const g4_bf16x8*)&Bs[n * LDK + quad * 8];
        }
        #pragma unroll
        for (int it = 0; it < 4; it++)
            #pragma unroll
            for (int jt = 0; jt < 4; jt++)
                acc[it][jt] = __builtin_amdgcn_mfma_f32_16x16x32_bf16(
                    afr[it], bfr[jt], acc[it][jt], 0, 0, 0);
        __syncthreads();
    }
    // ---- store, permuted columns: D col = lane&15, row = quad*4 + r
    #pragma unroll
    for (int it = 0; it < 4; it++) {
        #pragma unroll
        for (int jt = 0; jt < 4; jt++) {
            int gn   = bn + wc * 64 + jt * 16 + l15;
            int row0 = bm + wr * 64 + it * 16 + quad * 4;
            if (gn >= Nc) continue;
            int pn = g4_perm(gn);
            #pragma unroll
            for (int r = 0; r < 4; r++) {
                int gm = row0 + r;
                if (gm < M) C[(size_t)gm * Nc + pn] = g4_f2bf(acc[it][jt][r]);
            }
        }
    }
}

// ---------------------------------------------------------------------------
// Per-node attention logits from permuted h. One wave per node; lane = c.
// ---------------------------------------------------------------------------
__global__ __launch_bounds__(256) void g4_logits(
    const unsigned short* __restrict__ h, const void* __restrict__ att_src,
    const void* __restrict__ att_dst, const int* __restrict__ flags,
    float* __restrict__ a_src, float* __restrict__ a_dst) {
    int wid  = (blockIdx.x * blockDim.x + threadIdx.x) >> 6;
    int lane = threadIdx.x & 63;
    if (wid >= NN) return;
    const int isf = flags[0];
    const unsigned short* hp = h + ((size_t)wid << 8) + (lane << 2);
    uint2 hv = *(const uint2*)hp;
    float hvf[4];
    hvf[0] = __uint_as_float(hv.x << 16);
    hvf[1] = __uint_as_float(hv.x & 0xffff0000u);
    hvf[2] = __uint_as_float(hv.y << 16);
    hvf[3] = __uint_as_float(hv.y & 0xffff0000u);
    float s[4], d[4];
    #pragma unroll
    for (int hh = 0; hh < 4; hh++) {
        s[hh] = hvf[hh] * g4_ld(att_src, hh * 64 + lane, isf);
        d[hh] = hvf[hh] * g4_ld(att_dst, hh * 64 + lane, isf);
    }
    for (int off = 32; off > 0; off >>= 1) {
        #pragma unroll
        for (int hh = 0; hh < 4; hh++) {
            s[hh] += __shfl_down(s[hh], off);
            d[hh] += __shfl_down(d[hh], off);
        }
    }
    if (lane == 0) {
        #pragma unroll
        for (int hh = 0; hh < 4; hh++) {
            a_src[wid * 4 + hh] = s[hh];
            a_dst[wid * 4 + hh] = d[hh];
        }
    }
}

// ---------------------------------------------------------------------------
// Edge-parallel softmax: 1) logits + atomicMax  2) exp + atomicAdd  3) norm
// ---------------------------------------------------------------------------
__global__ void g4_edge1(const int* __restrict__ col, const int* __restrict__ dstarr,
                         const float* __restrict__ a_src, const float* __restrict__ a_dst,
                         float* __restrict__ alpha, unsigned int* __restrict__ encmax) {
    int i = blockIdx.x * 256 + threadIdx.x;
    if (i >= ETOT) return;
    int s = col[i], d = dstarr[i];
    g4_f32x4 as = *(const g4_f32x4*)(a_src + 4 * (size_t)s);
    g4_f32x4 ad = *(const g4_f32x4*)(a_dst + 4 * (size_t)d);
    g4_f32x4 e;
    #pragma unroll
    for (int hh = 0; hh < 4; hh++) {
        float v = as[hh] + ad[hh];
        e[hh] = (v > 0.f) ? v : NEG_SLOPE * v;
        atomicMax(&encmax[d * 4 + hh], g4_enc(e[hh]));
    }
    *(g4_f32x4*)(alpha + 4 * (size_t)i) = e;
}

__global__ void g4_edge2(const int* __restrict__ dstarr,
                         const unsigned int* __restrict__ encmax,
                         float* __restrict__ alpha, float* __restrict__ denom) {
    int i = blockIdx.x * 256 + threadIdx.x;
    if (i >= ETOT) return;
    int d = dstarr[i];
    g4_f32x4 e = *(const g4_f32x4*)(alpha + 4 * (size_t)i);
    g4_f32x4 ex;
    #pragma unroll
    for (int hh = 0; hh < 4; hh++) {
        float m = g4_dec(encmax[d * 4 + hh]);
        ex[hh] = __expf(e[hh] - m);
        atomicAdd(&denom[d * 4 + hh], ex[hh]);
    }
    *(g4_f32x4*)(alpha + 4 * (size_t)i) = ex;
}

__global__ void g4_edge3(const int* __restrict__ dstarr,
                         const float* __restrict__ denom, float* __restrict__ alpha) {
    int i = blockIdx.x * 256 + threadIdx.x;
    if (i >= ETOT) return;
    int d = dstarr[i];
    g4_f32x4 ex = *(const g4_f32x4*)(alpha + 4 * (size_t)i);
    g4_f32x4 dn = *(const g4_f32x4*)(denom + 4 * (size_t)d);
    #pragma unroll
    for (int hh = 0; hh < 4; hh++) ex[hh] = ex[hh] / dn[hh];
    *(g4_f32x4*)(alpha + 4 * (size_t)i) = ex;
}

// ---------------------------------------------------------------------------
// Gather: out[d] = sum_e alpha_e * h[src_e]  (+bias, ELU). Wave per dst.
// h is channel-permuted: lane reads 4 bf16 (heads 0..3 of channel c=lane).
// ---------------------------------------------------------------------------
__global__ __launch_bounds__(256) void g4_gather(
    const unsigned short* __restrict__ h, const float* __restrict__ alpha,
    const int* __restrict__ rowptr, const int* __restrict__ col,
    const void* __restrict__ bias, const int* __restrict__ flags,
    unsigned short* __restrict__ xout) {
    int d    = (blockIdx.x * blockDim.x + threadIdx.x) >> 6;
    int lane = threadIdx.x & 63;
    if (d >= NN) return;
    d = __builtin_amdgcn_readfirstlane(d);
    const int isf = flags[0];
    const int start = __builtin_amdgcn_readfirstlane(rowptr[d]);
    const int end   = __builtin_amdgcn_readfirstlane(rowptr[d + 1]);
    float a0 = 0.f, a1 = 0.f, a2 = 0.f, a3 = 0.f;
    // every node has >=1 edge (self-loop)
    int e = start;
    int sN = __builtin_amdgcn_readfirstlane(col[e]);
    g4_f32x4 alN = *(const g4_f32x4*)(alpha + 4 * (size_t)e);
    while (e < end) {
        int s = sN;
        g4_f32x4 al = alN;
        int e2 = e + 1;
        if (e2 < end) {
            sN = __builtin_amdgcn_readfirstlane(col[e2]);
            alN = *(const g4_f32x4*)(alpha + 4 * (size_t)e2);
        }
        uint2 hv = *(const uint2*)(h + ((size_t)s << 8) + (lane << 2));
        a0 = fmaf(__uint_as_float(hv.x << 16),          al[0], a0);
        a1 = fmaf(__uint_as_float(hv.x & 0xffff0000u),  al[1], a1);
        a2 = fmaf(__uint_as_float(hv.y << 16),          al[2], a2);
        a3 = fmaf(__uint_as_float(hv.y & 0xffff0000u),  al[3], a3);
        e = e2;
    }
    float acc[4] = {a0, a1, a2, a3};
    unsigned short ov[4];
    #pragma unroll
    for (int hh = 0; hh < 4; hh++) {
        float v = acc[hh] + g4_ld(bias, hh * 64 + lane, isf);
        v = (v > 0.f) ? v : (__expf(v) - 1.f);
        ov[hh] = g4_f2bf(v);
    }
    uint2 pack;
    pack.x = (unsigned int)ov[0] | ((unsigned int)ov[1] << 16);
    pack.y = (unsigned int)ov[2] | ((unsigned int)ov[3] << 16);
    *(uint2*)(xout + ((size_t)d << 8) + (lane << 2)) = pack;
}

// ---------------------------------------------------------------------------
// Fused MLP head (x is channel-permuted; w1 rows de-permuted at stage time)
// ---------------------------------------------------------------------------
__global__ __launch_bounds__(256) void g4_head2(
    const unsigned short* __restrict__ x, const void* __restrict__ w1,
    const void* __restrict__ b1, const void* __restrict__ w2,
    const void* __restrict__ b2, const int* __restrict__ flags,
    void* __restrict__ outp) {
    __shared__ float As[64][17];
    __shared__ float Bs[16][64];
    __shared__ float red[64][17];
    const int isf = flags[0];
    const int tid = threadIdx.x;
    const int bm  = blockIdx.x * 64;
    const int tx  = tid & 15;
    const int ty  = tid >> 4;
    float acc[4][4] = {};
    for (int k0 = 0; k0 < HC; k0 += 16) {
        for (int i = tid; i < 64 * 16; i += 256) {
            int m = i >> 4, kk = i & 15;
            int gm = bm + m;
            float v = 0.f;
            if (gm < NN) v = g4_bf2f(x[(size_t)gm * HC + k0 + kk]);
            As[m][kk] = v;
        }
        for (int i = tid; i < 16 * 64; i += 256) {
            int kk = i >> 6, n = i & 63;
            Bs[kk][n] = g4_ld(w1, (size_t)g4_operm(k0 + kk) * 64 + n, isf);
        }
        __syncthreads();
        #pragma unroll
        for (int kk = 0; kk < 16; ++kk) {
            float a[4], b[4];
            #pragma unroll
            for (int i = 0; i < 4; i++) a[i] = As[ty * 4 + i][kk];
            #pragma unroll
            for (int j = 0; j < 4; j++) b[j] = Bs[kk][tx * 4 + j];
            #pragma unroll
            for (int i = 0; i < 4; i++)
                #pragma unroll
                for (int j = 0; j < 4; j++) acc[i][j] += a[i] * b[j];
        }
        __syncthreads();
    }
    float b1v[4], w2v[4];
    #pragma unroll
    for (int j = 0; j < 4; j++) {
        b1v[j] = g4_ld(b1, tx * 4 + j, isf);
        w2v[j] = g4_ld(w2, tx * 4 + j, isf);
    }
    #pragma unroll
    for (int i = 0; i < 4; i++) {
        float s = 0.f;
        #pragma unroll
        for (int j = 0; j < 4; j++) {
            float v = acc[i][j] + b1v[j];
            v = fmaxf(v, 0.f);
            s += v * w2v[j];
        }
        red[ty * 4 + i][tx] = s;
    }
    __syncthreads();
    if (tid < 64) {
        float s = 0.f;
        #pragma unroll
        for (int g = 0; g < 16; g++) s += red[tid][g];
        int gm = bm + tid;
        if (gm < NN) {
            float r = s + g4_ld(b2, 0, isf);
            if (isf) ((float*)outp)[gm] = r;
            else     ((unsigned short*)outp)[gm] = g4_f2bf(r);
        }
    }
}

// ---------------------------------------------------------------------------
extern "C" __attribute__((visibility("default")))
void kernel_launch(void* const* d_in, const int* in_sizes, int n_in,
                   void* d_out, int out_size, void* d_ws, size_t ws_size,
                   hipStream_t stream) {
    const void* x_in = d_in[0];
    const int*  ei   = (const int*)d_in[1];
    const void* W[3]    = {d_in[2], d_in[6], d_in[10]};
    const void* ASRC[3] = {d_in[3], d_in[7], d_in[11]};
    const void* ADST[3] = {d_in[4], d_in[8], d_in[12]};
    const void* BIAS[3] = {d_in[5], d_in[9], d_in[13]};
    const void* hw1 = d_in[14];
    const void* hb1 = d_in[15];
    const void* hw2 = d_in[16];
    const void* hb2 = d_in[17];

    char* base = (char*)d_ws;
    size_t woff = 0;
#define G4_TAKE(name, type, count) \
    type* name = (type*)(base + woff); \
    woff += (((size_t)(count)) * sizeof(type) + 255) & ~(size_t)255;
    G4_TAKE(flags,   int, 8)
    G4_TAKE(deg,     int, NN)
    G4_TAKE(cnt,     int, NN)
    G4_TAKE(tmp,     int, NN)
    G4_TAKE(partial, int, 256)
    G4_TAKE(rowptr,  int, NN + 1)
    G4_TAKE(col,     int, ETOT)
    G4_TAKE(dstarr,  int, ETOT)
    G4_TAKE(asr,     float, (size_t)NN * 4)
    G4_TAKE(adsb,    float, (size_t)NN * 4)
    G4_TAKE(encmax,  unsigned int, (size_t)NN * 4)
    G4_TAKE(denom,   float, (size_t)NN * 4)
    G4_TAKE(alpha,   float, (size_t)ETOT * 4)
    G4_TAKE(hbuf,    unsigned short, (size_t)NN * HC)
    G4_TAKE(xbuf,    unsigned short, (size_t)NN * HC)
#undef G4_TAKE

    const int SCAN_BLOCKS = (NN + 255) / 256;          // 196
    const int EDGE_BLOCKS = (ETOT + 255) / 256;        // 3321
    const int WAVE_BLOCKS = (NN + 3) / 4;              // 12500
    const int TILE_BLOCKS = (NN + 63) / 64;            // 782
    const int NZ2_BLOCKS  = (NN * 4 + 255) / 256;      // 782

    g4_detect<<<1, 256, 0, stream>>>((const unsigned int*)x_in, ei, flags);
    g4_zero<<<SCAN_BLOCKS, 256, 0, stream>>>(deg, cnt, (unsigned int*)d_out);

    g4_hist<<<EDGE_BLOCKS, 256, 0, stream>>>(ei, flags, deg);
    g4_scan_block<<<SCAN_BLOCKS, 256, 0, stream>>>(deg, tmp, partial);
    g4_scan_partial<<<1, 256, 0, stream>>>(partial, SCAN_BLOCKS, rowptr + NN);
    g4_scan_add<<<SCAN_BLOCKS, 256, 0, stream>>>(tmp, partial, rowptr);
    g4_fill_csr<<<EDGE_BLOCKS, 256, 0, stream>>>(ei, flags, rowptr, cnt, col, dstarr);

    dim3 mgrid((NN + 127) / 128, HC / 128);
    for (int l = 0; l < 3; l++) {
        if (l == 0) {
            g4_gemm_mfma<<<mgrid, 256, 0, stream>>>(x_in, 0, W[l], 0, flags, hbuf, NN, 61, HC);
        } else {
            g4_gemm_mfma<<<mgrid, 256, 0, stream>>>(xbuf, 1, W[l], 1, flags, hbuf, NN, HC, HC);
        }
        g4_logits<<<WAVE_BLOCKS, 256, 0, stream>>>(hbuf, ASRC[l], ADST[l], flags, asr, adsb);
        g4_zero2<<<NZ2_BLOCKS, 256, 0, stream>>>(encmax, denom);
        g4_edge1<<<EDGE_BLOCKS, 256, 0, stream>>>(col, dstarr, asr, adsb, alpha, encmax);
        g4_edge2<<<EDGE_BLOCKS, 256, 0, stream>>>(dstarr, encmax, alpha, denom);
        g4_edge3<<<EDGE_BLOCKS, 256, 0, stream>>>(dstarr, denom, alpha);
        g4_gather<<<WAVE_BLOCKS, 256, 0, stream>>>(hbuf, alpha, rowptr, col,
                                                   BIAS[l], flags, xbuf);
    }
    g4_head2<<<TILE_BLOCKS, 256, 0, stream>>>(xbuf, hw1, hb1, hw2, hb2, flags, d_out);
}

// Round 8
// 920.151 us; speedup vs baseline: 2.0768x; 2.0768x over previous
//
#include <hip/hip_runtime.h>
#include <cstdint>
#include <cstddef>

// Problem constants (from reference)
#define NN   50000
#define EE   800000
#define ETOT (EE + NN)      // + self loops
#define HC   256            // H*C
#define NEG_SLOPE 0.2f
#define SENT_WORDS 25000
#define SENT_VAL 0x42C80000u

typedef __attribute__((ext_vector_type(8))) short g4_bf16x8;
typedef __attribute__((ext_vector_type(4))) float g4_f32x4;

// ---- bf16 helpers (raw ushort, explicit RNE) ------------------------------
__device__ __forceinline__ float g4_bf2f(unsigned short h) {
    union { unsigned int u; float f; } v;
    v.u = ((unsigned int)h) << 16;
    return v.f;
}
__device__ __forceinline__ unsigned short g4_f2bf(float f) {
    union { float f; unsigned int u; } v;
    v.f = f;
    unsigned int u = v.u;
    u += 0x7fffu + ((u >> 16) & 1u);   // round-to-nearest-even
    return (unsigned short)(u >> 16);
}
__device__ __forceinline__ float g4_ld(const void* p, size_t i, int isf) {
    return isf ? ((const float*)p)[i] : g4_bf2f(((const unsigned short*)p)[i]);
}
// channel permutation: stored pos p = c*4 + head  (c = within-head channel)
__device__ __forceinline__ int g4_perm(int o)  { return (o & 63) * 4 + (o >> 6); }
__device__ __forceinline__ int g4_operm(int p) { return (p & 3) * 64 + (p >> 2); }

// ---------------------------------------------------------------------------
// Dtype detection
// ---------------------------------------------------------------------------
__global__ void g4_detect(const unsigned int* __restrict__ xw,
                          const int* __restrict__ ei32, int* __restrict__ flags) {
    __shared__ int cnt[256];
    int t = threadIdx.x;
    unsigned int w = xw[t];
    int e = (int)((w >> 23) & 0xffu);
    cnt[t] = (e >= 110 && e <= 135) ? 1 : 0;
    __syncthreads();
    for (int off = 128; off > 0; off >>= 1) {
        if (t < off) cnt[t] += cnt[t + off];
        __syncthreads();
    }
    if (t == 0) {
        flags[0] = (cnt[0] >= 128) ? 1 : 0;
        int i64 = (ei32[1] == 0 && ei32[3] == 0 && ei32[5] == 0 &&
                   ei32[7] == 0 && ei32[9] == 0) ? 1 : 0;
        flags[1] = i64;
    }
}

// ---------------------------------------------------------------------------
// Zero CSR counters + d_out sentinel
// ---------------------------------------------------------------------------
__global__ void g4_zero(int* __restrict__ deg, int* __restrict__ cnt,
                        unsigned int* __restrict__ outw) {
    int i = blockIdx.x * 256 + threadIdx.x;
    if (i < NN) { deg[i] = 0; cnt[i] = 0; }
    if (i < SENT_WORDS) outw[i] = SENT_VAL;
}

// ---------------------------------------------------------------------------
// CSR build
// ---------------------------------------------------------------------------
__global__ void g4_hist(const int* __restrict__ ei, const int* __restrict__ flags,
                        int* __restrict__ deg) {
    int e = blockIdx.x * blockDim.x + threadIdx.x;
    if (e >= ETOT) return;
    int i64 = flags[1];
    int d;
    if (e < EE) d = i64 ? ei[2 * (EE + e)] : ei[EE + e];
    else        d = e - EE;
    atomicAdd(&deg[d], 1);
}

__global__ void g4_scan_block(const int* __restrict__ deg, int* __restrict__ tmp,
                              int* __restrict__ partial) {
    __shared__ int sh[256];
    int i = blockIdx.x * 256 + threadIdx.x;
    int v = (i < NN) ? deg[i] : 0;
    sh[threadIdx.x] = v;
    __syncthreads();
    for (int off = 1; off < 256; off <<= 1) {
        int t = (threadIdx.x >= off) ? sh[threadIdx.x - off] : 0;
        __syncthreads();
        sh[threadIdx.x] += t;
        __syncthreads();
    }
    if (i < NN) tmp[i] = sh[threadIdx.x] - v;
    if (threadIdx.x == 255) partial[blockIdx.x] = sh[255];
}

__global__ void g4_scan_partial(int* __restrict__ partial, int nb,
                                int* __restrict__ rowptrN) {
    __shared__ int sh[256];
    int v = (threadIdx.x < nb) ? partial[threadIdx.x] : 0;
    sh[threadIdx.x] = v;
    __syncthreads();
    for (int off = 1; off < 256; off <<= 1) {
        int t = (threadIdx.x >= off) ? sh[threadIdx.x - off] : 0;
        __syncthreads();
        sh[threadIdx.x] += t;
        __syncthreads();
    }
    if (threadIdx.x < nb) partial[threadIdx.x] = sh[threadIdx.x] - v;
    if (threadIdx.x == 0) *rowptrN = ETOT;
}

__global__ void g4_scan_add(const int* __restrict__ tmp, const int* __restrict__ partial,
                            int* __restrict__ rowptr) {
    int i = blockIdx.x * 256 + threadIdx.x;
    if (i < NN) rowptr[i] = tmp[i] + partial[blockIdx.x];
}

__global__ void g4_fill_csr(const int* __restrict__ ei, const int* __restrict__ flags,
                            const int* __restrict__ rowptr,
                            int* __restrict__ cnt, int* __restrict__ col,
                            int* __restrict__ dstarr) {
    int e = blockIdx.x * blockDim.x + threadIdx.x;
    if (e >= ETOT) return;
    int i64 = flags[1];
    int s, d;
    if (e < EE) {
        s = i64 ? ei[2 * e] : ei[e];
        d = i64 ? ei[2 * (EE + e)] : ei[EE + e];
    } else {
        s = e - EE; d = e - EE;
    }
    int pos = rowptr[d] + atomicAdd(&cnt[d], 1);
    col[pos] = s;
    dstarr[pos] = d;
}

// ---------------------------------------------------------------------------
// MFMA GEMM: C[M,Nc](bf16, channel-permuted cols) = A[M,K] @ B[K,Nc].
// permB: A columns are stored-permuted -> read B row g4_operm(gk).
// ---------------------------------------------------------------------------
#define LDK 40
__global__ __launch_bounds__(256) void g4_gemm_mfma(
    const void* __restrict__ A, int a_mode, const void* __restrict__ B, int permB,
    const int* __restrict__ flags, unsigned short* __restrict__ C,
    int M, int K, int Nc) {
    __shared__ short As[128 * LDK];
    __shared__ short Bs[128 * LDK];
    const int isf = flags[0];
    const int af  = (a_mode == 0) ? isf : 0;
    const int tid  = threadIdx.x;
    const int lane = tid & 63;
    const int wave = tid >> 6;
    const int wr = wave >> 1;
    const int wc = wave & 1;
    const int quad = lane >> 4;
    const int l15  = lane & 15;
    const int bm = blockIdx.x * 128;
    const int bn = blockIdx.y * 128;
    const int a_vec = (af == 0) && ((K & 15) == 0);

    g4_f32x4 acc[4][4];
    #pragma unroll
    for (int it = 0; it < 4; it++)
        #pragma unroll
        for (int jt = 0; jt < 4; jt++) {
            acc[it][jt].x = 0.f; acc[it][jt].y = 0.f;
            acc[it][jt].z = 0.f; acc[it][jt].w = 0.f;
        }

    for (int k0 = 0; k0 < K; k0 += 32) {
        // ---- stage A tile
        {
            int row = tid >> 1;
            int kc  = (tid & 1) * 16;
            int gm  = bm + row;
            short v[16];
            if (a_vec && gm < M && (k0 + kc + 16) <= K) {
                const short* ap = (const short*)A + (size_t)gm * K + k0 + kc;
                *(g4_bf16x8*)&v[0] = *(const g4_bf16x8*)ap;
                *(g4_bf16x8*)&v[8] = *(const g4_bf16x8*)(ap + 8);
            } else {
                #pragma unroll
                for (int j = 0; j < 16; j++) {
                    int gk = k0 + kc + j;
                    if (gm < M && gk < K) {
                        if (af == 0) v[j] = ((const short*)A)[(size_t)gm * K + gk];
                        else         v[j] = (short)g4_f2bf(((const float*)A)[(size_t)gm * K + gk]);
                    } else v[j] = 0;
                }
            }
            short* dst = &As[row * LDK + kc];
            *(g4_bf16x8*)dst       = *(g4_bf16x8*)&v[0];
            *(g4_bf16x8*)(dst + 8) = *(g4_bf16x8*)&v[8];
        }
        // ---- stage B tile transposed: Bs[n][k]; row permuted if permB
        {
            int n  = tid & 127;
            int kc = (tid >> 7) * 16;
            int gn = bn + n;
            short v[16];
            #pragma unroll
            for (int j = 0; j < 16; j++) {
                int gk = k0 + kc + j;
                if (gk < K && gn < Nc) {
                    int row = permB ? g4_operm(gk) : gk;
                    if (isf == 0) v[j] = ((const short*)B)[(size_t)row * Nc + gn];
                    else          v[j] = (short)g4_f2bf(((const float*)B)[(size_t)row * Nc + gn]);
                } else v[j] = 0;
            }
            short* dst = &Bs[n * LDK + kc];
            *(g4_bf16x8*)dst       = *(g4_bf16x8*)&v[0];
            *(g4_bf16x8*)(dst + 8) = *(g4_bf16x8*)&v[8];
        }
        __syncthreads();
        g4_bf16x8 afr[4], bfr[4];
        #pragma unroll
        for (int it = 0; it < 4; it++) {
            int m = wr * 64 + it * 16 + l15;
            afr[it] = *(const g4_bf16x8*)&As[m * LDK + quad * 8];
        }
        #pragma unroll
        for (int jt = 0; jt < 4; jt++) {
            int n = wc * 64 + jt * 16 + l15;
            bfr[jt] = *(const g4_bf16x8*)&Bs[n * LDK + quad * 8];
        }
        #pragma unroll
        for (int it = 0; it < 4; it++)
            #pragma unroll
            for (int jt = 0; jt < 4; jt++)
                acc[it][jt] = __builtin_amdgcn_mfma_f32_16x16x32_bf16(
                    afr[it], bfr[jt], acc[it][jt], 0, 0, 0);
        __syncthreads();
    }
    // ---- store, permuted columns: D col = lane&15, row = quad*4 + r
    #pragma unroll
    for (int it = 0; it < 4; it++) {
        #pragma unroll
        for (int jt = 0; jt < 4; jt++) {
            int gn   = bn + wc * 64 + jt * 16 + l15;
            int row0 = bm + wr * 64 + it * 16 + quad * 4;
            if (gn >= Nc) continue;
            int pn = g4_perm(gn);
            #pragma unroll
            for (int r = 0; r < 4; r++) {
                int gm = row0 + r;
                if (gm < M) C[(size_t)gm * Nc + pn] = g4_f2bf(acc[it][jt][r]);
            }
        }
    }
}

// ---------------------------------------------------------------------------
// Per-node attention logits from permuted h. One wave per node; lane = c.
// ---------------------------------------------------------------------------
__global__ __launch_bounds__(256) void g4_logits(
    const unsigned short* __restrict__ h, const void* __restrict__ att_src,
    const void* __restrict__ att_dst, const int* __restrict__ flags,
    float* __restrict__ a_src, float* __restrict__ a_dst) {
    int wid  = (blockIdx.x * blockDim.x + threadIdx.x) >> 6;
    int lane = threadIdx.x & 63;
    if (wid >= NN) return;
    const int isf = flags[0];
    const unsigned short* hp = h + ((size_t)wid << 8) + (lane << 2);
    uint2 hv = *(const uint2*)hp;
    float hvf[4];
    hvf[0] = __uint_as_float(hv.x << 16);
    hvf[1] = __uint_as_float(hv.x & 0xffff0000u);
    hvf[2] = __uint_as_float(hv.y << 16);
    hvf[3] = __uint_as_float(hv.y & 0xffff0000u);
    float s[4], d[4];
    #pragma unroll
    for (int hh = 0; hh < 4; hh++) {
        s[hh] = hvf[hh] * g4_ld(att_src, hh * 64 + lane, isf);
        d[hh] = hvf[hh] * g4_ld(att_dst, hh * 64 + lane, isf);
    }
    for (int off = 32; off > 0; off >>= 1) {
        #pragma unroll
        for (int hh = 0; hh < 4; hh++) {
            s[hh] += __shfl_down(s[hh], off);
            d[hh] += __shfl_down(d[hh], off);
        }
    }
    if (lane == 0) {
        #pragma unroll
        for (int hh = 0; hh < 4; hh++) {
            a_src[wid * 4 + hh] = s[hh];
            a_dst[wid * 4 + hh] = d[hh];
        }
    }
}

// ---------------------------------------------------------------------------
// Per-dst softmax stats, NO atomics. Wave per dst; lanes stride edges.
// Sweep 1: max. Sweep 2: exp(e-mx) -> alpha[] (un-normalized) + sum.
// Writes nodeinv[d][h] = 1/sum.
// ---------------------------------------------------------------------------
__global__ __launch_bounds__(256) void g4_nodestat(
    const int* __restrict__ rowptr, const int* __restrict__ col,
    const float* __restrict__ a_src, const float* __restrict__ a_dst,
    float* __restrict__ alpha, float* __restrict__ nodeinv) {
    int d    = (blockIdx.x * blockDim.x + threadIdx.x) >> 6;
    int lane = threadIdx.x & 63;
    if (d >= NN) return;
    const int start = rowptr[d], end = rowptr[d + 1];
    g4_f32x4 ad = *(const g4_f32x4*)(a_dst + 4 * (size_t)d);

    float mx[4] = {-1e30f, -1e30f, -1e30f, -1e30f};
    for (int i = start + lane; i < end; i += 64) {
        int s = col[i];
        g4_f32x4 as = *(const g4_f32x4*)(a_src + 4 * (size_t)s);
        #pragma unroll
        for (int hh = 0; hh < 4; hh++) {
            float e = as[hh] + ad[hh];
            e = (e > 0.f) ? e : NEG_SLOPE * e;
            mx[hh] = fmaxf(mx[hh], e);
        }
    }
    for (int off = 32; off > 0; off >>= 1)
        #pragma unroll
        for (int hh = 0; hh < 4; hh++) mx[hh] = fmaxf(mx[hh], __shfl_xor(mx[hh], off));

    float sm[4] = {0.f, 0.f, 0.f, 0.f};
    for (int i = start + lane; i < end; i += 64) {
        int s = col[i];
        g4_f32x4 as = *(const g4_f32x4*)(a_src + 4 * (size_t)s);
        g4_f32x4 ex;
        #pragma unroll
        for (int hh = 0; hh < 4; hh++) {
            float e = as[hh] + ad[hh];
            e = (e > 0.f) ? e : NEG_SLOPE * e;
            ex[hh] = __expf(e - mx[hh]);
            sm[hh] += ex[hh];
        }
        *(g4_f32x4*)(alpha + 4 * (size_t)i) = ex;   // un-normalized
    }
    for (int off = 32; off > 0; off >>= 1)
        #pragma unroll
        for (int hh = 0; hh < 4; hh++) sm[hh] += __shfl_xor(sm[hh], off);
    if (lane == 0) {
        g4_f32x4 inv;
        #pragma unroll
        for (int hh = 0; hh < 4; hh++) inv[hh] = 1.f / sm[hh];
        *(g4_f32x4*)(nodeinv + 4 * (size_t)d) = inv;
    }
}

// ---------------------------------------------------------------------------
// Edge-parallel normalize: alpha[e] *= nodeinv[dst[e]]. No atomics.
// ---------------------------------------------------------------------------
__global__ void g4_alphanorm(const int* __restrict__ dstarr,
                             const float* __restrict__ nodeinv,
                             float* __restrict__ alpha) {
    int i = blockIdx.x * 256 + threadIdx.x;
    if (i >= ETOT) return;
    int d = dstarr[i];
    g4_f32x4 ex = *(const g4_f32x4*)(alpha + 4 * (size_t)i);
    g4_f32x4 inv = *(const g4_f32x4*)(nodeinv + 4 * (size_t)d);
    #pragma unroll
    for (int hh = 0; hh < 4; hh++) ex[hh] *= inv[hh];
    *(g4_f32x4*)(alpha + 4 * (size_t)i) = ex;
}

// ---------------------------------------------------------------------------
// Gather: out[d] = sum_e alpha_e * h[src_e]  (+bias, ELU). Wave per dst.
// h is channel-permuted: lane reads 4 bf16 (heads 0..3 of channel c=lane).
// ---------------------------------------------------------------------------
__global__ __launch_bounds__(256) void g4_gather(
    const unsigned short* __restrict__ h, const float* __restrict__ alpha,
    const int* __restrict__ rowptr, const int* __restrict__ col,
    const void* __restrict__ bias, const int* __restrict__ flags,
    unsigned short* __restrict__ xout) {
    int d    = (blockIdx.x * blockDim.x + threadIdx.x) >> 6;
    int lane = threadIdx.x & 63;
    if (d >= NN) return;
    d = __builtin_amdgcn_readfirstlane(d);
    const int isf = flags[0];
    const int start = __builtin_amdgcn_readfirstlane(rowptr[d]);
    const int end   = __builtin_amdgcn_readfirstlane(rowptr[d + 1]);
    float a0 = 0.f, a1 = 0.f, a2 = 0.f, a3 = 0.f;
    int e = start;
    int sN = __builtin_amdgcn_readfirstlane(col[e]);
    g4_f32x4 alN = *(const g4_f32x4*)(alpha + 4 * (size_t)e);
    while (e < end) {
        int s = sN;
        g4_f32x4 al = alN;
        int e2 = e + 1;
        if (e2 < end) {
            sN = __builtin_amdgcn_readfirstlane(col[e2]);
            alN = *(const g4_f32x4*)(alpha + 4 * (size_t)e2);
        }
        uint2 hv = *(const uint2*)(h + ((size_t)s << 8) + (lane << 2));
        a0 = fmaf(__uint_as_float(hv.x << 16),          al[0], a0);
        a1 = fmaf(__uint_as_float(hv.x & 0xffff0000u),  al[1], a1);
        a2 = fmaf(__uint_as_float(hv.y << 16),          al[2], a2);
        a3 = fmaf(__uint_as_float(hv.y & 0xffff0000u),  al[3], a3);
        e = e2;
    }
    float acc[4] = {a0, a1, a2, a3};
    unsigned short ov[4];
    #pragma unroll
    for (int hh = 0; hh < 4; hh++) {
        float v = acc[hh] + g4_ld(bias, hh * 64 + lane, isf);
        v = (v > 0.f) ? v : (__expf(v) - 1.f);
        ov[hh] = g4_f2bf(v);
    }
    uint2 pack;
    pack.x = (unsigned int)ov[0] | ((unsigned int)ov[1] << 16);
    pack.y = (unsigned int)ov[2] | ((unsigned int)ov[3] << 16);
    *(uint2*)(xout + ((size_t)d << 8) + (lane << 2)) = pack;
}

// ---------------------------------------------------------------------------
// Fused MLP head (x is channel-permuted; w1 rows de-permuted at stage time)
// ---------------------------------------------------------------------------
__global__ __launch_bounds__(256) void g4_head2(
    const unsigned short* __restrict__ x, const void* __restrict__ w1,
    const void* __restrict__ b1, const void* __restrict__ w2,
    const void* __restrict__ b2, const int* __restrict__ flags,
    void* __restrict__ outp) {
    __shared__ float As[64][17];
    __shared__ float Bs[16][64];
    __shared__ float red[64][17];
    const int isf = flags[0];
    const int tid = threadIdx.x;
    const int bm  = blockIdx.x * 64;
    const int tx  = tid & 15;
    const int ty  = tid >> 4;
    float acc[4][4] = {};
    for (int k0 = 0; k0 < HC; k0 += 16) {
        for (int i = tid; i < 64 * 16; i += 256) {
            int m = i >> 4, kk = i & 15;
            int gm = bm + m;
            float v = 0.f;
            if (gm < NN) v = g4_bf2f(x[(size_t)gm * HC + k0 + kk]);
            As[m][kk] = v;
        }
        for (int i = tid; i < 16 * 64; i += 256) {
            int kk = i >> 6, n = i & 63;
            Bs[kk][n] = g4_ld(w1, (size_t)g4_operm(k0 + kk) * 64 + n, isf);
        }
        __syncthreads();
        #pragma unroll
        for (int kk = 0; kk < 16; ++kk) {
            float a[4], b[4];
            #pragma unroll
            for (int i = 0; i < 4; i++) a[i] = As[ty * 4 + i][kk];
            #pragma unroll
            for (int j = 0; j < 4; j++) b[j] = Bs[kk][tx * 4 + j];
            #pragma unroll
            for (int i = 0; i < 4; i++)
                #pragma unroll
                for (int j = 0; j < 4; j++) acc[i][j] += a[i] * b[j];
        }
        __syncthreads();
    }
    float b1v[4], w2v[4];
    #pragma unroll
    for (int j = 0; j < 4; j++) {
        b1v[j] = g4_ld(b1, tx * 4 + j, isf);
        w2v[j] = g4_ld(w2, tx * 4 + j, isf);
    }
    #pragma unroll
    for (int i = 0; i < 4; i++) {
        float s = 0.f;
        #pragma unroll
        for (int j = 0; j < 4; j++) {
            float v = acc[i][j] + b1v[j];
            v = fmaxf(v, 0.f);
            s += v * w2v[j];
        }
        red[ty * 4 + i][tx] = s;
    }
    __syncthreads();
    if (tid < 64) {
        float s = 0.f;
        #pragma unroll
        for (int g = 0; g < 16; g++) s += red[tid][g];
        int gm = bm + tid;
        if (gm < NN) {
            float r = s + g4_ld(b2, 0, isf);
            if (isf) ((float*)outp)[gm] = r;
            else     ((unsigned short*)outp)[gm] = g4_f2bf(r);
        }
    }
}

// ---------------------------------------------------------------------------
extern "C" __attribute__((visibility("default")))
void kernel_launch(void* const* d_in, const int* in_sizes, int n_in,
                   void* d_out, int out_size, void* d_ws, size_t ws_size,
                   hipStream_t stream) {
    const void* x_in = d_in[0];
    const int*  ei   = (const int*)d_in[1];
    const void* W[3]    = {d_in[2], d_in[6], d_in[10]};
    const void* ASRC[3] = {d_in[3], d_in[7], d_in[11]};
    const void* ADST[3] = {d_in[4], d_in[8], d_in[12]};
    const void* BIAS[3] = {d_in[5], d_in[9], d_in[13]};
    const void* hw1 = d_in[14];
    const void* hb1 = d_in[15];
    const void* hw2 = d_in[16];
    const void* hb2 = d_in[17];

    char* base = (char*)d_ws;
    size_t woff = 0;
#define G4_TAKE(name, type, count) \
    type* name = (type*)(base + woff); \
    woff += (((size_t)(count)) * sizeof(type) + 255) & ~(size_t)255;
    G4_TAKE(flags,   int, 8)
    G4_TAKE(deg,     int, NN)
    G4_TAKE(cnt,     int, NN)
    G4_TAKE(tmp,     int, NN)
    G4_TAKE(partial, int, 256)
    G4_TAKE(rowptr,  int, NN + 1)
    G4_TAKE(col,     int, ETOT)
    G4_TAKE(dstarr,  int, ETOT)
    G4_TAKE(asr,     float, (size_t)NN * 4)
    G4_TAKE(adsb,    float, (size_t)NN * 4)
    G4_TAKE(nodeinv, float, (size_t)NN * 4)
    G4_TAKE(alpha,   float, (size_t)ETOT * 4)
    G4_TAKE(hbuf,    unsigned short, (size_t)NN * HC)
    G4_TAKE(xbuf,    unsigned short, (size_t)NN * HC)
#undef G4_TAKE

    const int SCAN_BLOCKS = (NN + 255) / 256;          // 196
    const int EDGE_BLOCKS = (ETOT + 255) / 256;        // 3321
    const int WAVE_BLOCKS = (NN + 3) / 4;              // 12500
    const int TILE_BLOCKS = (NN + 63) / 64;            // 782

    g4_detect<<<1, 256, 0, stream>>>((const unsigned int*)x_in, ei, flags);
    g4_zero<<<SCAN_BLOCKS, 256, 0, stream>>>(deg, cnt, (unsigned int*)d_out);

    g4_hist<<<EDGE_BLOCKS, 256, 0, stream>>>(ei, flags, deg);
    g4_scan_block<<<SCAN_BLOCKS, 256, 0, stream>>>(deg, tmp, partial);
    g4_scan_partial<<<1, 256, 0, stream>>>(partial, SCAN_BLOCKS, rowptr + NN);
    g4_scan_add<<<SCAN_BLOCKS, 256, 0, stream>>>(tmp, partial, rowptr);
    g4_fill_csr<<<EDGE_BLOCKS, 256, 0, stream>>>(ei, flags, rowptr, cnt, col, dstarr);

    dim3 mgrid((NN + 127) / 128, HC / 128);
    for (int l = 0; l < 3; l++) {
        if (l == 0) {
            g4_gemm_mfma<<<mgrid, 256, 0, stream>>>(x_in, 0, W[l], 0, flags, hbuf, NN, 61, HC);
        } else {
            g4_gemm_mfma<<<mgrid, 256, 0, stream>>>(xbuf, 1, W[l], 1, flags, hbuf, NN, HC, HC);
        }
        g4_logits<<<WAVE_BLOCKS, 256, 0, stream>>>(hbuf, ASRC[l], ADST[l], flags, asr, adsb);
        g4_nodestat<<<WAVE_BLOCKS, 256, 0, stream>>>(rowptr, col, asr, adsb, alpha, nodeinv);
        g4_alphanorm<<<EDGE_BLOCKS, 256, 0, stream>>>(dstarr, nodeinv, alpha);
        g4_gather<<<WAVE_BLOCKS, 256, 0, stream>>>(hbuf, alpha, rowptr, col,
                                                   BIAS[l], flags, xbuf);
    }
    g4_head2<<<TILE_BLOCKS, 256, 0, stream>>>(xbuf, hw1, hb1, hw2, hb2, flags, d_out);
}

// Round 9
// 637.161 us; speedup vs baseline: 2.9992x; 1.4441x over previous
//
#include <hip/hip_runtime.h>
#include <cstdint>
#include <cstddef>

#define NN   50000
#define EE   800000
#define ETOT (EE + NN)
#define HC   256
#define NEG_SLOPE 0.2f
#define SENT_WORDS 25000
#define SENT_VAL 0x42C80000u

typedef __attribute__((ext_vector_type(8))) short g4_bf16x8;
typedef __attribute__((ext_vector_type(4))) float g4_f32x4;

__device__ __forceinline__ float g4_bf2f(unsigned short h) {
    union { unsigned int u; float f; } v;
    v.u = ((unsigned int)h) << 16;
    return v.f;
}
__device__ __forceinline__ unsigned short g4_f2bf(float f) {
    union { float f; unsigned int u; } v;
    v.f = f;
    unsigned int u = v.u;
    u += 0x7fffu + ((u >> 16) & 1u);   // RNE
    return (unsigned short)(u >> 16);
}
__device__ __forceinline__ float g4_ld(const void* p, size_t i, int isf) {
    return isf ? ((const float*)p)[i] : g4_bf2f(((const unsigned short*)p)[i]);
}

// ---------------------------------------------------------------------------
__global__ void g4_detect(const unsigned int* __restrict__ xw,
                          const int* __restrict__ ei32, int* __restrict__ flags) {
    __shared__ int cnt[256];
    int t = threadIdx.x;
    unsigned int w = xw[t];
    int e = (int)((w >> 23) & 0xffu);
    cnt[t] = (e >= 110 && e <= 135) ? 1 : 0;
    __syncthreads();
    for (int off = 128; off > 0; off >>= 1) {
        if (t < off) cnt[t] += cnt[t + off];
        __syncthreads();
    }
    if (t == 0) {
        flags[0] = (cnt[0] >= 128) ? 1 : 0;
        int i64 = (ei32[1] == 0 && ei32[3] == 0 && ei32[5] == 0 &&
                   ei32[7] == 0 && ei32[9] == 0) ? 1 : 0;
        flags[1] = i64;
    }
}

__global__ void g4_zero(int* __restrict__ deg, int* __restrict__ cnt,
                        unsigned int* __restrict__ outw) {
    int i = blockIdx.x * 256 + threadIdx.x;
    if (i < NN) { deg[i] = 0; cnt[i] = 0; }
    if (i < SENT_WORDS) outw[i] = SENT_VAL;
}

// ---------------------------------------------------------------------------
// CSR build
// ---------------------------------------------------------------------------
__global__ void g4_hist(const int* __restrict__ ei, const int* __restrict__ flags,
                        int* __restrict__ deg) {
    int e = blockIdx.x * blockDim.x + threadIdx.x;
    if (e >= ETOT) return;
    int i64 = flags[1];
    int d;
    if (e < EE) d = i64 ? ei[2 * (EE + e)] : ei[EE + e];
    else        d = e - EE;
    atomicAdd(&deg[d], 1);
}

__global__ void g4_scan_block(const int* __restrict__ deg, int* __restrict__ tmp,
                              int* __restrict__ partial) {
    __shared__ int sh[256];
    int i = blockIdx.x * 256 + threadIdx.x;
    int v = (i < NN) ? deg[i] : 0;
    sh[threadIdx.x] = v;
    __syncthreads();
    for (int off = 1; off < 256; off <<= 1) {
        int t = (threadIdx.x >= off) ? sh[threadIdx.x - off] : 0;
        __syncthreads();
        sh[threadIdx.x] += t;
        __syncthreads();
    }
    if (i < NN) tmp[i] = sh[threadIdx.x] - v;
    if (threadIdx.x == 255) partial[blockIdx.x] = sh[255];
}

__global__ void g4_scan_partial(int* __restrict__ partial, int nb,
                                int* __restrict__ rowptrN) {
    __shared__ int sh[256];
    int v = (threadIdx.x < nb) ? partial[threadIdx.x] : 0;
    sh[threadIdx.x] = v;
    __syncthreads();
    for (int off = 1; off < 256; off <<= 1) {
        int t = (threadIdx.x >= off) ? sh[threadIdx.x - off] : 0;
        __syncthreads();
        sh[threadIdx.x] += t;
        __syncthreads();
    }
    if (threadIdx.x < nb) partial[threadIdx.x] = sh[threadIdx.x] - v;
    if (threadIdx.x == 0) *rowptrN = ETOT;
}

__global__ void g4_scan_add(const int* __restrict__ tmp, const int* __restrict__ partial,
                            int* __restrict__ rowptr) {
    int i = blockIdx.x * 256 + threadIdx.x;
    if (i < NN) rowptr[i] = tmp[i] + partial[blockIdx.x];
}

__global__ void g4_fill_csr(const int* __restrict__ ei, const int* __restrict__ flags,
                            const int* __restrict__ rowptr,
                            int* __restrict__ cnt, int* __restrict__ col) {
    int e = blockIdx.x * blockDim.x + threadIdx.x;
    if (e >= ETOT) return;
    int i64 = flags[1];
    int s, d;
    if (e < EE) {
        s = i64 ? ei[2 * e] : ei[e];
        d = i64 ? ei[2 * (EE + e)] : ei[EE + e];
    } else {
        s = e - EE; d = e - EE;
    }
    int pos = rowptr[d] + atomicAdd(&cnt[d], 1);
    col[pos] = s;
}

// ---------------------------------------------------------------------------
// Weight prep: Bt[n][k] (bf16, K zero-padded to KP) from B[k][n] (dtype flags).
// KP is a power of two (64 or 256); kshift = log2(KP).
// ---------------------------------------------------------------------------
__global__ void g4_bprep(const void* __restrict__ B, const int* __restrict__ flags,
                         unsigned short* __restrict__ Bt, int K, int kshift, int Nc) {
    int i = blockIdx.x * 256 + threadIdx.x;
    int KP = 1 << kshift;
    if (i >= Nc << kshift) return;
    int n = i >> kshift;
    int k = i & (KP - 1);
    unsigned short v = 0;
    if (k < K) {
        if (flags[0]) v = g4_f2bf(((const float*)B)[(size_t)k * Nc + n]);
        else          v = ((const unsigned short*)B)[(size_t)k * Nc + n];
    }
    Bt[(size_t)n * KP + k] = v;
}

// ---------------------------------------------------------------------------
// MFMA GEMM + fused attention logits.
// C[M,256](bf16) = A[M,K] @ B  (B pre-transposed in Bt[n][KP]).
// 64x256 block tile (full N), 256 threads = 4 waves, wave w = head w's 64 cols.
// Epilogue: C store + per-row dot with att_src/att_dst -> a_srcO/a_dstO.
// ---------------------------------------------------------------------------
#define LDK 40
__global__ __launch_bounds__(256) void g4_gemm2(
    const void* __restrict__ A, int a_mode, const unsigned short* __restrict__ Bt,
    const int* __restrict__ flags, unsigned short* __restrict__ C,
    const void* __restrict__ att_src, const void* __restrict__ att_dst,
    float* __restrict__ a_srcO, float* __restrict__ a_dstO,
    int M, int K, int KP) {
    __shared__ short As[64 * LDK];
    __shared__ short Bs[256 * LDK];
    const int isf = flags[0];
    const int af  = (a_mode == 0) ? isf : 0;
    const int tid  = threadIdx.x;
    const int lane = tid & 63;
    const int wc   = tid >> 6;       // wave = head
    const int quad = lane >> 4;
    const int l15  = lane & 15;
    const int bm = blockIdx.x * 64;
    const int a_vec = (af == 0) && ((K & 31) == 0);

    g4_f32x4 acc[4][4];
    #pragma unroll
    for (int it = 0; it < 4; it++)
        #pragma unroll
        for (int jt = 0; jt < 4; jt++) {
            acc[it][jt].x = 0.f; acc[it][jt].y = 0.f;
            acc[it][jt].z = 0.f; acc[it][jt].w = 0.f;
        }

    for (int k0 = 0; k0 < KP; k0 += 32) {
        // A tile: 64 rows x 32 k. thread: row=tid>>2, kc=(tid&3)*8 (one b128)
        {
            int row = tid >> 2, kc = (tid & 3) * 8;
            int gm = bm + row;
            short v[8];
            if (a_vec && gm < M) {
                *(g4_bf16x8*)v = *(const g4_bf16x8*)((const short*)A + (size_t)gm * K + k0 + kc);
            } else {
                #pragma unroll
                for (int j = 0; j < 8; j++) {
                    int gk = k0 + kc + j;
                    if (gm < M && gk < K) {
                        if (af == 0) v[j] = ((const short*)A)[(size_t)gm * K + gk];
                        else         v[j] = (short)g4_f2bf(((const float*)A)[(size_t)gm * K + gk]);
                    } else v[j] = 0;
                }
            }
            *(g4_bf16x8*)&As[row * LDK + kc] = *(g4_bf16x8*)v;
        }
        // B tile: 256 n-rows x 32 k. thread tid = row n, 4 b128 loads
        {
            const unsigned short* bp = Bt + (size_t)tid * KP + k0;
            short* dst = &Bs[tid * LDK];
            *(g4_bf16x8*)(dst + 0)  = *(const g4_bf16x8*)(bp + 0);
            *(g4_bf16x8*)(dst + 8)  = *(const g4_bf16x8*)(bp + 8);
            *(g4_bf16x8*)(dst + 16) = *(const g4_bf16x8*)(bp + 16);
            *(g4_bf16x8*)(dst + 24) = *(const g4_bf16x8*)(bp + 24);
        }
        __syncthreads();
        g4_bf16x8 afr[4], bfr[4];
        #pragma unroll
        for (int it = 0; it < 4; it++)
            afr[it] = *(const g4_bf16x8*)&As[(it * 16 + l15) * LDK + quad * 8];
        #pragma unroll
        for (int jt = 0; jt < 4; jt++)
            bfr[jt] = *(const g4_bf16x8*)&Bs[(wc * 64 + jt * 16 + l15) * LDK + quad * 8];
        #pragma unroll
        for (int it = 0; it < 4; it++)
            #pragma unroll
            for (int jt = 0; jt < 4; jt++)
                acc[it][jt] = __builtin_amdgcn_mfma_f32_16x16x32_bf16(
                    afr[it], bfr[jt], acc[it][jt], 0, 0, 0);
        __syncthreads();
    }
    // ---- C store (natural layout): D col = l15, row = quad*4 + r
    #pragma unroll
    for (int it = 0; it < 4; it++) {
        #pragma unroll
        for (int jt = 0; jt < 4; jt++) {
            int gn   = wc * 64 + jt * 16 + l15;
            int row0 = bm + it * 16 + quad * 4;
            #pragma unroll
            for (int r = 0; r < 4; r++) {
                int gm = row0 + r;
                if (gm < M) C[(size_t)gm * HC + gn] = g4_f2bf(acc[it][jt][r]);
            }
        }
    }
    // ---- fused logits: per-row dot over this wave's 64 cols (= head wc)
    float asv[4], adv[4];
    #pragma unroll
    for (int jt = 0; jt < 4; jt++) {
        asv[jt] = g4_ld(att_src, wc * 64 + jt * 16 + l15, isf);
        adv[jt] = g4_ld(att_dst, wc * 64 + jt * 16 + l15, isf);
    }
    #pragma unroll
    for (int it = 0; it < 4; it++) {
        #pragma unroll
        for (int r = 0; r < 4; r++) {
            float ps = 0.f, pd = 0.f;
            #pragma unroll
            for (int jt = 0; jt < 4; jt++) {
                ps += acc[it][jt][r] * asv[jt];
                pd += acc[it][jt][r] * adv[jt];
            }
            #pragma unroll
            for (int off = 1; off < 16; off <<= 1) {
                ps += __shfl_xor(ps, off);
                pd += __shfl_xor(pd, off);
            }
            if (l15 == 0) {
                int gm = bm + it * 16 + quad * 4 + r;
                if (gm < M) {
                    a_srcO[gm * 4 + wc] = ps;
                    a_dstO[gm * 4 + wc] = pd;
                }
            }
        }
    }
}

// ---------------------------------------------------------------------------
// Per-dst softmax stats, no atomics. Wave per dst; lanes stride edges.
// alpha[] gets UN-normalized exp; nodeinv[d][h] = 1/sum.
// ---------------------------------------------------------------------------
__global__ __launch_bounds__(256) void g4_nodestat(
    const int* __restrict__ rowptr, const int* __restrict__ col,
    const float* __restrict__ a_src, const float* __restrict__ a_dst,
    float* __restrict__ alpha, float* __restrict__ nodeinv) {
    int d    = (blockIdx.x * blockDim.x + threadIdx.x) >> 6;
    int lane = threadIdx.x & 63;
    if (d >= NN) return;
    const int start = rowptr[d], end = rowptr[d + 1];
    g4_f32x4 ad = *(const g4_f32x4*)(a_dst + 4 * (size_t)d);

    float mx[4] = {-1e30f, -1e30f, -1e30f, -1e30f};
    for (int i = start + lane; i < end; i += 64) {
        int s = col[i];
        g4_f32x4 as = *(const g4_f32x4*)(a_src + 4 * (size_t)s);
        #pragma unroll
        for (int hh = 0; hh < 4; hh++) {
            float e = as[hh] + ad[hh];
            e = (e > 0.f) ? e : NEG_SLOPE * e;
            mx[hh] = fmaxf(mx[hh], e);
        }
    }
    for (int off = 32; off > 0; off >>= 1)
        #pragma unroll
        for (int hh = 0; hh < 4; hh++) mx[hh] = fmaxf(mx[hh], __shfl_xor(mx[hh], off));

    float sm[4] = {0.f, 0.f, 0.f, 0.f};
    for (int i = start + lane; i < end; i += 64) {
        int s = col[i];
        g4_f32x4 as = *(const g4_f32x4*)(a_src + 4 * (size_t)s);
        g4_f32x4 ex;
        #pragma unroll
        for (int hh = 0; hh < 4; hh++) {
            float e = as[hh] + ad[hh];
            e = (e > 0.f) ? e : NEG_SLOPE * e;
            ex[hh] = __expf(e - mx[hh]);
            sm[hh] += ex[hh];
        }
        *(g4_f32x4*)(alpha + 4 * (size_t)i) = ex;
    }
    for (int off = 32; off > 0; off >>= 1)
        #pragma unroll
        for (int hh = 0; hh < 4; hh++) sm[hh] += __shfl_xor(sm[hh], off);
    if (lane == 0) {
        g4_f32x4 inv;
        #pragma unroll
        for (int hh = 0; hh < 4; hh++) inv[hh] = 1.f / sm[hh];
        *(g4_f32x4*)(nodeinv + 4 * (size_t)d) = inv;
    }
}

// ---------------------------------------------------------------------------
// Gather (natural layout): lane covers channels lane*4..lane*4+3, head=lane>>4.
// out[d] = (sum_e exp_e * h[src_e]) * nodeinv[d] + bias -> ELU -> bf16.
// ---------------------------------------------------------------------------
__global__ __launch_bounds__(256) void g4_gather(
    const unsigned short* __restrict__ h, const float* __restrict__ alpha,
    const int* __restrict__ rowptr, const int* __restrict__ col,
    const float* __restrict__ nodeinv, const void* __restrict__ bias,
    const int* __restrict__ flags, unsigned short* __restrict__ xout) {
    int d    = (blockIdx.x * blockDim.x + threadIdx.x) >> 6;
    int lane = threadIdx.x & 63;
    if (d >= NN) return;
    d = __builtin_amdgcn_readfirstlane(d);
    const int isf = flags[0];
    const int hd  = lane >> 4;
    const int start = __builtin_amdgcn_readfirstlane(rowptr[d]);
    const int end   = __builtin_amdgcn_readfirstlane(rowptr[d + 1]);
    float a0 = 0.f, a1 = 0.f, a2 = 0.f, a3 = 0.f;
    int e = start;
    int sN = __builtin_amdgcn_readfirstlane(col[e]);
    g4_f32x4 alv = *(const g4_f32x4*)(alpha + 4 * (size_t)e);
    while (e < end) {
        int s = sN;
        float al = (hd < 2) ? ((hd == 0) ? alv.x : alv.y)
                            : ((hd == 2) ? alv.z : alv.w);
        int e2 = e + 1;
        if (e2 < end) {
            sN  = __builtin_amdgcn_readfirstlane(col[e2]);
            alv = *(const g4_f32x4*)(alpha + 4 * (size_t)e2);
        }
        uint2 hv = *(const uint2*)(h + ((size_t)s << 8) + (lane << 2));
        a0 = fmaf(__uint_as_float(hv.x << 16),          al, a0);
        a1 = fmaf(__uint_as_float(hv.x & 0xffff0000u),  al, a1);
        a2 = fmaf(__uint_as_float(hv.y << 16),          al, a2);
        a3 = fmaf(__uint_as_float(hv.y & 0xffff0000u),  al, a3);
        e = e2;
    }
    g4_f32x4 invv = *(const g4_f32x4*)(nodeinv + 4 * (size_t)d);
    float inv = (hd < 2) ? ((hd == 0) ? invv.x : invv.y)
                         : ((hd == 2) ? invv.z : invv.w);
    float acc[4] = {a0 * inv, a1 * inv, a2 * inv, a3 * inv};
    unsigned short ov[4];
    #pragma unroll
    for (int j = 0; j < 4; j++) {
        float v = acc[j] + g4_ld(bias, (lane << 2) + j, isf);
        v = (v > 0.f) ? v : (__expf(v) - 1.f);
        ov[j] = g4_f2bf(v);
    }
    uint2 pack;
    pack.x = (unsigned int)ov[0] | ((unsigned int)ov[1] << 16);
    pack.y = (unsigned int)ov[2] | ((unsigned int)ov[3] << 16);
    *(uint2*)(xout + ((size_t)d << 8) + (lane << 2)) = pack;
}

// ---------------------------------------------------------------------------
// Fused MLP head (natural layout)
// ---------------------------------------------------------------------------
__global__ __launch_bounds__(256) void g4_head2(
    const unsigned short* __restrict__ x, const void* __restrict__ w1,
    const void* __restrict__ b1, const void* __restrict__ w2,
    const void* __restrict__ b2, const int* __restrict__ flags,
    void* __restrict__ outp) {
    __shared__ float As[64][17];
    __shared__ float Bs[16][64];
    __shared__ float red[64][17];
    const int isf = flags[0];
    const int tid = threadIdx.x;
    const int bm  = blockIdx.x * 64;
    const int tx  = tid & 15;
    const int ty  = tid >> 4;
    float acc[4][4] = {};
    for (int k0 = 0; k0 < HC; k0 += 16) {
        for (int i = tid; i < 64 * 16; i += 256) {
            int m = i >> 4, kk = i & 15;
            int gm = bm + m;
            float v = 0.f;
            if (gm < NN) v = g4_bf2f(x[(size_t)gm * HC + k0 + kk]);
            As[m][kk] = v;
        }
        for (int i = tid; i < 16 * 64; i += 256) {
            int kk = i >> 6, n = i & 63;
            Bs[kk][n] = g4_ld(w1, (size_t)(k0 + kk) * 64 + n, isf);
        }
        __syncthreads();
        #pragma unroll
        for (int kk = 0; kk < 16; ++kk) {
            float a[4], b[4];
            #pragma unroll
            for (int i = 0; i < 4; i++) a[i] = As[ty * 4 + i][kk];
            #pragma unroll
            for (int j = 0; j < 4; j++) b[j] = Bs[kk][tx * 4 + j];
            #pragma unroll
            for (int i = 0; i < 4; i++)
                #pragma unroll
                for (int j = 0; j < 4; j++) acc[i][j] += a[i] * b[j];
        }
        __syncthreads();
    }
    float b1v[4], w2v[4];
    #pragma unroll
    for (int j = 0; j < 4; j++) {
        b1v[j] = g4_ld(b1, tx * 4 + j, isf);
        w2v[j] = g4_ld(w2, tx * 4 + j, isf);
    }
    #pragma unroll
    for (int i = 0; i < 4; i++) {
        float s = 0.f;
        #pragma unroll
        for (int j = 0; j < 4; j++) {
            float v = acc[i][j] + b1v[j];
            v = fmaxf(v, 0.f);
            s += v * w2v[j];
        }
        red[ty * 4 + i][tx] = s;
    }
    __syncthreads();
    if (tid < 64) {
        float s = 0.f;
        #pragma unroll
        for (int g = 0; g < 16; g++) s += red[tid][g];
        int gm = bm + tid;
        if (gm < NN) {
            float r = s + g4_ld(b2, 0, isf);
            if (isf) ((float*)outp)[gm] = r;
            else     ((unsigned short*)outp)[gm] = g4_f2bf(r);
        }
    }
}

// ---------------------------------------------------------------------------
extern "C" __attribute__((visibility("default")))
void kernel_launch(void* const* d_in, const int* in_sizes, int n_in,
                   void* d_out, int out_size, void* d_ws, size_t ws_size,
                   hipStream_t stream) {
    const void* x_in = d_in[0];
    const int*  ei   = (const int*)d_in[1];
    const void* W[3]    = {d_in[2], d_in[6], d_in[10]};
    const void* ASRC[3] = {d_in[3], d_in[7], d_in[11]};
    const void* ADST[3] = {d_in[4], d_in[8], d_in[12]};
    const void* BIAS[3] = {d_in[5], d_in[9], d_in[13]};
    const void* hw1 = d_in[14];
    const void* hb1 = d_in[15];
    const void* hw2 = d_in[16];
    const void* hb2 = d_in[17];

    char* base = (char*)d_ws;
    size_t woff = 0;
#define G4_TAKE(name, type, count) \
    type* name = (type*)(base + woff); \
    woff += (((size_t)(count)) * sizeof(type) + 255) & ~(size_t)255;
    G4_TAKE(flags,   int, 8)
    G4_TAKE(deg,     int, NN)
    G4_TAKE(cnt,     int, NN)
    G4_TAKE(tmp,     int, NN)
    G4_TAKE(partial, int, 256)
    G4_TAKE(rowptr,  int, NN + 1)
    G4_TAKE(col,     int, ETOT)
    G4_TAKE(asr,     float, (size_t)NN * 4)
    G4_TAKE(adsb,    float, (size_t)NN * 4)
    G4_TAKE(nodeinv, float, (size_t)NN * 4)
    G4_TAKE(alpha,   float, (size_t)ETOT * 4)
    G4_TAKE(Bt,      unsigned short, (size_t)HC * HC)
    G4_TAKE(hbuf,    unsigned short, (size_t)NN * HC)
    G4_TAKE(xbuf,    unsigned short, (size_t)NN * HC)
#undef G4_TAKE

    const int SCAN_BLOCKS = (NN + 255) / 256;          // 196
    const int EDGE_BLOCKS = (ETOT + 255) / 256;        // 3321
    const int WAVE_BLOCKS = (NN + 3) / 4;              // 12500
    const int TILE_BLOCKS = (NN + 63) / 64;            // 782

    g4_detect<<<1, 256, 0, stream>>>((const unsigned int*)x_in, ei, flags);
    g4_zero<<<SCAN_BLOCKS, 256, 0, stream>>>(deg, cnt, (unsigned int*)d_out);

    g4_hist<<<EDGE_BLOCKS, 256, 0, stream>>>(ei, flags, deg);
    g4_scan_block<<<SCAN_BLOCKS, 256, 0, stream>>>(deg, tmp, partial);
    g4_scan_partial<<<1, 256, 0, stream>>>(partial, SCAN_BLOCKS, rowptr + NN);
    g4_scan_add<<<SCAN_BLOCKS, 256, 0, stream>>>(tmp, partial, rowptr);
    g4_fill_csr<<<EDGE_BLOCKS, 256, 0, stream>>>(ei, flags, rowptr, cnt, col);

    for (int l = 0; l < 3; l++) {
        int K      = (l == 0) ? 61 : HC;
        int kshift = (l == 0) ? 6  : 8;     // KP = 64 or 256
        int KP     = 1 << kshift;
        int pb     = ((HC << kshift) + 255) / 256;
        g4_bprep<<<pb, 256, 0, stream>>>(W[l], flags, Bt, K, kshift, HC);
        if (l == 0) {
            g4_gemm2<<<TILE_BLOCKS, 256, 0, stream>>>(x_in, 0, Bt, flags, hbuf,
                ASRC[l], ADST[l], asr, adsb, NN, K, KP);
        } else {
            g4_gemm2<<<TILE_BLOCKS, 256, 0, stream>>>(xbuf, 1, Bt, flags, hbuf,
                ASRC[l], ADST[l], asr, adsb, NN, K, KP);
        }
        g4_nodestat<<<WAVE_BLOCKS, 256, 0, stream>>>(rowptr, col, asr, adsb, alpha, nodeinv);
        g4_gather<<<WAVE_BLOCKS, 256, 0, stream>>>(hbuf, alpha, rowptr, col,
                                                   nodeinv, BIAS[l], flags, xbuf);
    }
    g4_head2<<<TILE_BLOCKS, 256, 0, stream>>>(xbuf, hw1, hb1, hw2, hb2, flags, d_out);
}

// Round 10
// 606.388 us; speedup vs baseline: 3.1514x; 1.0507x over previous
//
#include <hip/hip_runtime.h>
#include <cstdint>
#include <cstddef>

#define NN   50000
#define EE   800000
#define ETOT (EE + NN)
#define HC   256
#define NEG_SLOPE 0.2f
#define SENT_WORDS 25000
#define SENT_VAL 0x42C80000u

typedef __attribute__((ext_vector_type(8))) short g4_bf16x8;
typedef __attribute__((ext_vector_type(4))) float g4_f32x4;

__device__ __forceinline__ float g4_bf2f(unsigned short h) {
    union { unsigned int u; float f; } v;
    v.u = ((unsigned int)h) << 16;
    return v.f;
}
__device__ __forceinline__ unsigned short g4_f2bf(float f) {
    union { float f; unsigned int u; } v;
    v.f = f;
    unsigned int u = v.u;
    u += 0x7fffu + ((u >> 16) & 1u);   // RNE
    return (unsigned short)(u >> 16);
}
__device__ __forceinline__ float g4_ld(const void* p, size_t i, int isf) {
    return isf ? ((const float*)p)[i] : g4_bf2f(((const unsigned short*)p)[i]);
}

// ---------------------------------------------------------------------------
__global__ void g4_detect(const unsigned int* __restrict__ xw,
                          const int* __restrict__ ei32, int* __restrict__ flags) {
    __shared__ int cnt[256];
    int t = threadIdx.x;
    unsigned int w = xw[t];
    int e = (int)((w >> 23) & 0xffu);
    cnt[t] = (e >= 110 && e <= 135) ? 1 : 0;
    __syncthreads();
    for (int off = 128; off > 0; off >>= 1) {
        if (t < off) cnt[t] += cnt[t + off];
        __syncthreads();
    }
    if (t == 0) {
        flags[0] = (cnt[0] >= 128) ? 1 : 0;
        int i64 = (ei32[1] == 0 && ei32[3] == 0 && ei32[5] == 0 &&
                   ei32[7] == 0 && ei32[9] == 0) ? 1 : 0;
        flags[1] = i64;
    }
}

__global__ void g4_zero(int* __restrict__ deg, int* __restrict__ cnt,
                        unsigned int* __restrict__ outw) {
    int i = blockIdx.x * 256 + threadIdx.x;
    if (i < NN) { deg[i] = 0; cnt[i] = 0; }
    if (i < SENT_WORDS) outw[i] = SENT_VAL;
}

// ---------------------------------------------------------------------------
// CSR build
// ---------------------------------------------------------------------------
__global__ void g4_hist(const int* __restrict__ ei, const int* __restrict__ flags,
                        int* __restrict__ deg) {
    int e = blockIdx.x * blockDim.x + threadIdx.x;
    if (e >= ETOT) return;
    int i64 = flags[1];
    int d;
    if (e < EE) d = i64 ? ei[2 * (EE + e)] : ei[EE + e];
    else        d = e - EE;
    atomicAdd(&deg[d], 1);
}

__global__ void g4_scan_block(const int* __restrict__ deg, int* __restrict__ tmp,
                              int* __restrict__ partial) {
    __shared__ int sh[256];
    int i = blockIdx.x * 256 + threadIdx.x;
    int v = (i < NN) ? deg[i] : 0;
    sh[threadIdx.x] = v;
    __syncthreads();
    for (int off = 1; off < 256; off <<= 1) {
        int t = (threadIdx.x >= off) ? sh[threadIdx.x - off] : 0;
        __syncthreads();
        sh[threadIdx.x] += t;
        __syncthreads();
    }
    if (i < NN) tmp[i] = sh[threadIdx.x] - v;
    if (threadIdx.x == 255) partial[blockIdx.x] = sh[255];
}

__global__ void g4_scan_partial(int* __restrict__ partial, int nb,
                                int* __restrict__ rowptrN) {
    __shared__ int sh[256];
    int v = (threadIdx.x < nb) ? partial[threadIdx.x] : 0;
    sh[threadIdx.x] = v;
    __syncthreads();
    for (int off = 1; off < 256; off <<= 1) {
        int t = (threadIdx.x >= off) ? sh[threadIdx.x - off] : 0;
        __syncthreads();
        sh[threadIdx.x] += t;
        __syncthreads();
    }
    if (threadIdx.x < nb) partial[threadIdx.x] = sh[threadIdx.x] - v;
    if (threadIdx.x == 0) *rowptrN = ETOT;
}

__global__ void g4_scan_add(const int* __restrict__ tmp, const int* __restrict__ partial,
                            int* __restrict__ rowptr) {
    int i = blockIdx.x * 256 + threadIdx.x;
    if (i < NN) rowptr[i] = tmp[i] + partial[blockIdx.x];
}

__global__ void g4_fill_csr(const int* __restrict__ ei, const int* __restrict__ flags,
                            const int* __restrict__ rowptr,
                            int* __restrict__ cnt, int* __restrict__ col) {
    int e = blockIdx.x * blockDim.x + threadIdx.x;
    if (e >= ETOT) return;
    int i64 = flags[1];
    int s, d;
    if (e < EE) {
        s = i64 ? ei[2 * e] : ei[e];
        d = i64 ? ei[2 * (EE + e)] : ei[EE + e];
    } else {
        s = e - EE; d = e - EE;
    }
    int pos = rowptr[d] + atomicAdd(&cnt[d], 1);
    col[pos] = s;
}

// ---------------------------------------------------------------------------
// Weight prep: Bt[n][k] (bf16, K zero-padded to KP) from B[k][n].
// ---------------------------------------------------------------------------
__global__ void g4_bprep(const void* __restrict__ B, const int* __restrict__ flags,
                         unsigned short* __restrict__ Bt, int K, int kshift, int Nc) {
    int i = blockIdx.x * 256 + threadIdx.x;
    int KP = 1 << kshift;
    if (i >= Nc << kshift) return;
    int n = i >> kshift;
    int k = i & (KP - 1);
    unsigned short v = 0;
    if (k < K) {
        if (flags[0]) v = g4_f2bf(((const float*)B)[(size_t)k * Nc + n]);
        else          v = ((const unsigned short*)B)[(size_t)k * Nc + n];
    }
    Bt[(size_t)n * KP + k] = v;
}

// ---------------------------------------------------------------------------
// MFMA GEMM + fused attention logits. 64x256 tile, 4 waves = 4 heads.
// ---------------------------------------------------------------------------
#define LDK 40
__global__ __launch_bounds__(256) void g4_gemm2(
    const void* __restrict__ A, int a_mode, const unsigned short* __restrict__ Bt,
    const int* __restrict__ flags, unsigned short* __restrict__ C,
    const void* __restrict__ att_src, const void* __restrict__ att_dst,
    float* __restrict__ a_srcO, float* __restrict__ a_dstO,
    int M, int K, int KP) {
    __shared__ short As[64 * LDK];
    __shared__ short Bs[256 * LDK];
    const int isf = flags[0];
    const int af  = (a_mode == 0) ? isf : 0;
    const int tid  = threadIdx.x;
    const int lane = tid & 63;
    const int wc   = tid >> 6;       // wave = head
    const int quad = lane >> 4;
    const int l15  = lane & 15;
    const int bm = blockIdx.x * 64;
    const int a_vec = (af == 0) && ((K & 31) == 0);

    g4_f32x4 acc[4][4];
    #pragma unroll
    for (int it = 0; it < 4; it++)
        #pragma unroll
        for (int jt = 0; jt < 4; jt++) {
            acc[it][jt].x = 0.f; acc[it][jt].y = 0.f;
            acc[it][jt].z = 0.f; acc[it][jt].w = 0.f;
        }

    for (int k0 = 0; k0 < KP; k0 += 32) {
        {
            int row = tid >> 2, kc = (tid & 3) * 8;
            int gm = bm + row;
            short v[8];
            if (a_vec && gm < M) {
                *(g4_bf16x8*)v = *(const g4_bf16x8*)((const short*)A + (size_t)gm * K + k0 + kc);
            } else {
                #pragma unroll
                for (int j = 0; j < 8; j++) {
                    int gk = k0 + kc + j;
                    if (gm < M && gk < K) {
                        if (af == 0) v[j] = ((const short*)A)[(size_t)gm * K + gk];
                        else         v[j] = (short)g4_f2bf(((const float*)A)[(size_t)gm * K + gk]);
                    } else v[j] = 0;
                }
            }
            *(g4_bf16x8*)&As[row * LDK + kc] = *(g4_bf16x8*)v;
        }
        {
            const unsigned short* bp = Bt + (size_t)tid * KP + k0;
            short* dst = &Bs[tid * LDK];
            *(g4_bf16x8*)(dst + 0)  = *(const g4_bf16x8*)(bp + 0);
            *(g4_bf16x8*)(dst + 8)  = *(const g4_bf16x8*)(bp + 8);
            *(g4_bf16x8*)(dst + 16) = *(const g4_bf16x8*)(bp + 16);
            *(g4_bf16x8*)(dst + 24) = *(const g4_bf16x8*)(bp + 24);
        }
        __syncthreads();
        g4_bf16x8 afr[4], bfr[4];
        #pragma unroll
        for (int it = 0; it < 4; it++)
            afr[it] = *(const g4_bf16x8*)&As[(it * 16 + l15) * LDK + quad * 8];
        #pragma unroll
        for (int jt = 0; jt < 4; jt++)
            bfr[jt] = *(const g4_bf16x8*)&Bs[(wc * 64 + jt * 16 + l15) * LDK + quad * 8];
        #pragma unroll
        for (int it = 0; it < 4; it++)
            #pragma unroll
            for (int jt = 0; jt < 4; jt++)
                acc[it][jt] = __builtin_amdgcn_mfma_f32_16x16x32_bf16(
                    afr[it], bfr[jt], acc[it][jt], 0, 0, 0);
        __syncthreads();
    }
    #pragma unroll
    for (int it = 0; it < 4; it++) {
        #pragma unroll
        for (int jt = 0; jt < 4; jt++) {
            int gn   = wc * 64 + jt * 16 + l15;
            int row0 = bm + it * 16 + quad * 4;
            #pragma unroll
            for (int r = 0; r < 4; r++) {
                int gm = row0 + r;
                if (gm < M) C[(size_t)gm * HC + gn] = g4_f2bf(acc[it][jt][r]);
            }
        }
    }
    float asv[4], adv[4];
    #pragma unroll
    for (int jt = 0; jt < 4; jt++) {
        asv[jt] = g4_ld(att_src, wc * 64 + jt * 16 + l15, isf);
        adv[jt] = g4_ld(att_dst, wc * 64 + jt * 16 + l15, isf);
    }
    #pragma unroll
    for (int it = 0; it < 4; it++) {
        #pragma unroll
        for (int r = 0; r < 4; r++) {
            float ps = 0.f, pd = 0.f;
            #pragma unroll
            for (int jt = 0; jt < 4; jt++) {
                ps += acc[it][jt][r] * asv[jt];
                pd += acc[it][jt][r] * adv[jt];
            }
            #pragma unroll
            for (int off = 1; off < 16; off <<= 1) {
                ps += __shfl_xor(ps, off);
                pd += __shfl_xor(pd, off);
            }
            if (l15 == 0) {
                int gm = bm + it * 16 + quad * 4 + r;
                if (gm < M) {
                    a_srcO[gm * 4 + wc] = ps;
                    a_dstO[gm * 4 + wc] = pd;
                }
            }
        }
    }
}

// ---------------------------------------------------------------------------
// Per-dst softmax stats, no atomics. alpha[] = un-normalized exp.
// ---------------------------------------------------------------------------
__global__ __launch_bounds__(256) void g4_nodestat(
    const int* __restrict__ rowptr, const int* __restrict__ col,
    const float* __restrict__ a_src, const float* __restrict__ a_dst,
    float* __restrict__ alpha, float* __restrict__ nodeinv) {
    int d    = (blockIdx.x * blockDim.x + threadIdx.x) >> 6;
    int lane = threadIdx.x & 63;
    if (d >= NN) return;
    const int start = rowptr[d], end = rowptr[d + 1];
    g4_f32x4 ad = *(const g4_f32x4*)(a_dst + 4 * (size_t)d);

    float mx[4] = {-1e30f, -1e30f, -1e30f, -1e30f};
    for (int i = start + lane; i < end; i += 64) {
        int s = col[i];
        g4_f32x4 as = *(const g4_f32x4*)(a_src + 4 * (size_t)s);
        #pragma unroll
        for (int hh = 0; hh < 4; hh++) {
            float e = as[hh] + ad[hh];
            e = (e > 0.f) ? e : NEG_SLOPE * e;
            mx[hh] = fmaxf(mx[hh], e);
        }
    }
    for (int off = 32; off > 0; off >>= 1)
        #pragma unroll
        for (int hh = 0; hh < 4; hh++) mx[hh] = fmaxf(mx[hh], __shfl_xor(mx[hh], off));

    float sm[4] = {0.f, 0.f, 0.f, 0.f};
    for (int i = start + lane; i < end; i += 64) {
        int s = col[i];
        g4_f32x4 as = *(const g4_f32x4*)(a_src + 4 * (size_t)s);
        g4_f32x4 ex;
        #pragma unroll
        for (int hh = 0; hh < 4; hh++) {
            float e = as[hh] + ad[hh];
            e = (e > 0.f) ? e : NEG_SLOPE * e;
            ex[hh] = __expf(e - mx[hh]);
            sm[hh] += ex[hh];
        }
        *(g4_f32x4*)(alpha + 4 * (size_t)i) = ex;
    }
    for (int off = 32; off > 0; off >>= 1)
        #pragma unroll
        for (int hh = 0; hh < 4; hh++) sm[hh] += __shfl_xor(sm[hh], off);
    if (lane == 0) {
        g4_f32x4 inv;
        #pragma unroll
        for (int hh = 0; hh < 4; hh++) inv[hh] = 1.f / sm[hh];
        *(g4_f32x4*)(nodeinv + 4 * (size_t)d) = inv;
    }
}

// ---------------------------------------------------------------------------
// Gather, 4-wide pipelined. Chunk of 16 edges: lanes cooperatively load
// col (64B broadcast) and alpha (256B coalesced; edge j head q -> lane 4j+q),
// then issue 4 independent h-loads per group. lane = channels lane*4..+3.
// ---------------------------------------------------------------------------
__global__ __launch_bounds__(256) void g4_gather(
    const unsigned short* __restrict__ h, const float* __restrict__ alpha,
    const int* __restrict__ rowptr, const int* __restrict__ col,
    const float* __restrict__ nodeinv, const void* __restrict__ bias,
    const int* __restrict__ flags, unsigned short* __restrict__ xout) {
    int d    = (blockIdx.x * blockDim.x + threadIdx.x) >> 6;
    int lane = threadIdx.x & 63;
    if (d >= NN) return;
    d = __builtin_amdgcn_readfirstlane(d);
    const int isf = flags[0];
    const int hd  = lane >> 4;
    const int l15 = lane & 15;
    const int start = __builtin_amdgcn_readfirstlane(rowptr[d]);
    const int end   = __builtin_amdgcn_readfirstlane(rowptr[d + 1]);
    float a0 = 0.f, a1 = 0.f, a2 = 0.f, a3 = 0.f;
    const size_t ch = (size_t)(lane << 2);
    for (int base = start; base < end; base += 16) {
        int m = end - base;
        if (m > 16) m = 16;
        int   cv = col[base + l15];                  // edges base..base+15 (x4 dup)
        float av = alpha[4 * (size_t)base + lane];   // component (e,q) -> lane 4e+q
        int j = 0;
        for (; j + 4 <= m; j += 4) {
            int s0 = __shfl(cv, j);
            int s1 = __shfl(cv, j + 1);
            int s2 = __shfl(cv, j + 2);
            int s3 = __shfl(cv, j + 3);
            float w0 = __shfl(av, 4 * j + hd);
            float w1 = __shfl(av, 4 * j + 4 + hd);
            float w2 = __shfl(av, 4 * j + 8 + hd);
            float w3 = __shfl(av, 4 * j + 12 + hd);
            uint2 h0 = *(const uint2*)(h + (((size_t)s0) << 8) + ch);
            uint2 h1 = *(const uint2*)(h + (((size_t)s1) << 8) + ch);
            uint2 h2 = *(const uint2*)(h + (((size_t)s2) << 8) + ch);
            uint2 h3 = *(const uint2*)(h + (((size_t)s3) << 8) + ch);
            a0 = fmaf(__uint_as_float(h0.x << 16),         w0, a0);
            a1 = fmaf(__uint_as_float(h0.x & 0xffff0000u), w0, a1);
            a2 = fmaf(__uint_as_float(h0.y << 16),         w0, a2);
            a3 = fmaf(__uint_as_float(h0.y & 0xffff0000u), w0, a3);
            a0 = fmaf(__uint_as_float(h1.x << 16),         w1, a0);
            a1 = fmaf(__uint_as_float(h1.x & 0xffff0000u), w1, a1);
            a2 = fmaf(__uint_as_float(h1.y << 16),         w1, a2);
            a3 = fmaf(__uint_as_float(h1.y & 0xffff0000u), w1, a3);
            a0 = fmaf(__uint_as_float(h2.x << 16),         w2, a0);
            a1 = fmaf(__uint_as_float(h2.x & 0xffff0000u), w2, a1);
            a2 = fmaf(__uint_as_float(h2.y << 16),         w2, a2);
            a3 = fmaf(__uint_as_float(h2.y & 0xffff0000u), w2, a3);
            a0 = fmaf(__uint_as_float(h3.x << 16),         w3, a0);
            a1 = fmaf(__uint_as_float(h3.x & 0xffff0000u), w3, a1);
            a2 = fmaf(__uint_as_float(h3.y << 16),         w3, a2);
            a3 = fmaf(__uint_as_float(h3.y & 0xffff0000u), w3, a3);
        }
        for (; j < m; j++) {
            int s = __shfl(cv, j);
            float w = __shfl(av, 4 * j + hd);
            uint2 hv = *(const uint2*)(h + (((size_t)s) << 8) + ch);
            a0 = fmaf(__uint_as_float(hv.x << 16),         w, a0);
            a1 = fmaf(__uint_as_float(hv.x & 0xffff0000u), w, a1);
            a2 = fmaf(__uint_as_float(hv.y << 16),         w, a2);
            a3 = fmaf(__uint_as_float(hv.y & 0xffff0000u), w, a3);
        }
    }
    g4_f32x4 invv = *(const g4_f32x4*)(nodeinv + 4 * (size_t)d);
    float inv = (hd < 2) ? ((hd == 0) ? invv.x : invv.y)
                         : ((hd == 2) ? invv.z : invv.w);
    float acc[4] = {a0 * inv, a1 * inv, a2 * inv, a3 * inv};
    unsigned short ov[4];
    #pragma unroll
    for (int j = 0; j < 4; j++) {
        float v = acc[j] + g4_ld(bias, (lane << 2) + j, isf);
        v = (v > 0.f) ? v : (__expf(v) - 1.f);
        ov[j] = g4_f2bf(v);
    }
    uint2 pack;
    pack.x = (unsigned int)ov[0] | ((unsigned int)ov[1] << 16);
    pack.y = (unsigned int)ov[2] | ((unsigned int)ov[3] << 16);
    *(uint2*)(xout + ((size_t)d << 8) + (lane << 2)) = pack;
}

// ---------------------------------------------------------------------------
// Fused MLP head
// ---------------------------------------------------------------------------
__global__ __launch_bounds__(256) void g4_head2(
    const unsigned short* __restrict__ x, const void* __restrict__ w1,
    const void* __restrict__ b1, const void* __restrict__ w2,
    const void* __restrict__ b2, const int* __restrict__ flags,
    void* __restrict__ outp) {
    __shared__ float As[64][17];
    __shared__ float Bs[16][64];
    __shared__ float red[64][17];
    const int isf = flags[0];
    const int tid = threadIdx.x;
    const int bm  = blockIdx.x * 64;
    const int tx  = tid & 15;
    const int ty  = tid >> 4;
    float acc[4][4] = {};
    for (int k0 = 0; k0 < HC; k0 += 16) {
        for (int i = tid; i < 64 * 16; i += 256) {
            int m = i >> 4, kk = i & 15;
            int gm = bm + m;
            float v = 0.f;
            if (gm < NN) v = g4_bf2f(x[(size_t)gm * HC + k0 + kk]);
            As[m][kk] = v;
        }
        for (int i = tid; i < 16 * 64; i += 256) {
            int kk = i >> 6, n = i & 63;
            Bs[kk][n] = g4_ld(w1, (size_t)(k0 + kk) * 64 + n, isf);
        }
        __syncthreads();
        #pragma unroll
        for (int kk = 0; kk < 16; ++kk) {
            float a[4], b[4];
            #pragma unroll
            for (int i = 0; i < 4; i++) a[i] = As[ty * 4 + i][kk];
            #pragma unroll
            for (int j = 0; j < 4; j++) b[j] = Bs[kk][tx * 4 + j];
            #pragma unroll
            for (int i = 0; i < 4; i++)
                #pragma unroll
                for (int j = 0; j < 4; j++) acc[i][j] += a[i] * b[j];
        }
        __syncthreads();
    }
    float b1v[4], w2v[4];
    #pragma unroll
    for (int j = 0; j < 4; j++) {
        b1v[j] = g4_ld(b1, tx * 4 + j, isf);
        w2v[j] = g4_ld(w2, tx * 4 + j, isf);
    }
    #pragma unroll
    for (int i = 0; i < 4; i++) {
        float s = 0.f;
        #pragma unroll
        for (int j = 0; j < 4; j++) {
            float v = acc[i][j] + b1v[j];
            v = fmaxf(v, 0.f);
            s += v * w2v[j];
        }
        red[ty * 4 + i][tx] = s;
    }
    __syncthreads();
    if (tid < 64) {
        float s = 0.f;
        #pragma unroll
        for (int g = 0; g < 16; g++) s += red[tid][g];
        int gm = bm + tid;
        if (gm < NN) {
            float r = s + g4_ld(b2, 0, isf);
            if (isf) ((float*)outp)[gm] = r;
            else     ((unsigned short*)outp)[gm] = g4_f2bf(r);
        }
    }
}

// ---------------------------------------------------------------------------
extern "C" __attribute__((visibility("default")))
void kernel_launch(void* const* d_in, const int* in_sizes, int n_in,
                   void* d_out, int out_size, void* d_ws, size_t ws_size,
                   hipStream_t stream) {
    const void* x_in = d_in[0];
    const int*  ei   = (const int*)d_in[1];
    const void* W[3]    = {d_in[2], d_in[6], d_in[10]};
    const void* ASRC[3] = {d_in[3], d_in[7], d_in[11]};
    const void* ADST[3] = {d_in[4], d_in[8], d_in[12]};
    const void* BIAS[3] = {d_in[5], d_in[9], d_in[13]};
    const void* hw1 = d_in[14];
    const void* hb1 = d_in[15];
    const void* hw2 = d_in[16];
    const void* hb2 = d_in[17];

    char* base = (char*)d_ws;
    size_t woff = 0;
#define G4_TAKE(name, type, count) \
    type* name = (type*)(base + woff); \
    woff += (((size_t)(count)) * sizeof(type) + 255) & ~(size_t)255;
    G4_TAKE(flags,   int, 8)
    G4_TAKE(deg,     int, NN)
    G4_TAKE(cnt,     int, NN)
    G4_TAKE(tmp,     int, NN)
    G4_TAKE(partial, int, 256)
    G4_TAKE(rowptr,  int, NN + 1)
    G4_TAKE(col,     int, ETOT + 16)                 // +16 pad (chunked reads)
    G4_TAKE(asr,     float, (size_t)NN * 4)
    G4_TAKE(adsb,    float, (size_t)NN * 4)
    G4_TAKE(nodeinv, float, (size_t)NN * 4)
    G4_TAKE(alpha,   float, (size_t)ETOT * 4 + 64)   // +64 pad (chunked reads)
    G4_TAKE(Bt,      unsigned short, (size_t)HC * HC)
    G4_TAKE(hbuf,    unsigned short, (size_t)NN * HC)
    G4_TAKE(xbuf,    unsigned short, (size_t)NN * HC)
#undef G4_TAKE

    const int SCAN_BLOCKS = (NN + 255) / 256;          // 196
    const int EDGE_BLOCKS = (ETOT + 255) / 256;        // 3321
    const int WAVE_BLOCKS = (NN + 3) / 4;              // 12500
    const int TILE_BLOCKS = (NN + 63) / 64;            // 782

    g4_detect<<<1, 256, 0, stream>>>((const unsigned int*)x_in, ei, flags);
    g4_zero<<<SCAN_BLOCKS, 256, 0, stream>>>(deg, cnt, (unsigned int*)d_out);

    g4_hist<<<EDGE_BLOCKS, 256, 0, stream>>>(ei, flags, deg);
    g4_scan_block<<<SCAN_BLOCKS, 256, 0, stream>>>(deg, tmp, partial);
    g4_scan_partial<<<1, 256, 0, stream>>>(partial, SCAN_BLOCKS, rowptr + NN);
    g4_scan_add<<<SCAN_BLOCKS, 256, 0, stream>>>(tmp, partial, rowptr);
    g4_fill_csr<<<EDGE_BLOCKS, 256, 0, stream>>>(ei, flags, rowptr, cnt, col);

    for (int l = 0; l < 3; l++) {
        int K      = (l == 0) ? 61 : HC;
        int kshift = (l == 0) ? 6  : 8;     // KP = 64 or 256
        int KP     = 1 << kshift;
        int pb     = ((HC << kshift) + 255) / 256;
        g4_bprep<<<pb, 256, 0, stream>>>(W[l], flags, Bt, K, kshift, HC);
        if (l == 0) {
            g4_gemm2<<<TILE_BLOCKS, 256, 0, stream>>>(x_in, 0, Bt, flags, hbuf,
                ASRC[l], ADST[l], asr, adsb, NN, K, KP);
        } else {
            g4_gemm2<<<TILE_BLOCKS, 256, 0, stream>>>(xbuf, 1, Bt, flags, hbuf,
                ASRC[l], ADST[l], asr, adsb, NN, K, KP);
        }
        g4_nodestat<<<WAVE_BLOCKS, 256, 0, stream>>>(rowptr, col, asr, adsb, alpha, nodeinv);
        g4_gather<<<WAVE_BLOCKS, 256, 0, stream>>>(hbuf, alpha, rowptr, col,
                                                   nodeinv, BIAS[l], flags, xbuf);
    }
    g4_head2<<<TILE_BLOCKS, 256, 0, stream>>>(xbuf, hw1, hb1, hw2, hb2, flags, d_out);
}

// Round 11
// 541.238 us; speedup vs baseline: 3.5308x; 1.1204x over previous
//
#include <hip/hip_runtime.h>
#include <cstdint>
#include <cstddef>

#define NN   50000
#define EE   800000
#define ETOT (EE + NN)
#define HC   256
#define NEG_SLOPE 0.2f
#define SENT_WORDS 25000
#define SENT_VAL 0x42C80000u

typedef __attribute__((ext_vector_type(8))) short g4_bf16x8;
typedef __attribute__((ext_vector_type(4))) float g4_f32x4;

__device__ __forceinline__ float g4_bf2f(unsigned short h) {
    union { unsigned int u; float f; } v;
    v.u = ((unsigned int)h) << 16;
    return v.f;
}
__device__ __forceinline__ unsigned short g4_f2bf(float f) {
    union { float f; unsigned int u; } v;
    v.f = f;
    unsigned int u = v.u;
    u += 0x7fffu + ((u >> 16) & 1u);   // RNE
    return (unsigned short)(u >> 16);
}
__device__ __forceinline__ float g4_ld(const void* p, size_t i, int isf) {
    return isf ? ((const float*)p)[i] : g4_bf2f(((const unsigned short*)p)[i]);
}

// ---------------------------------------------------------------------------
__global__ void g4_detect(const unsigned int* __restrict__ xw,
                          const int* __restrict__ ei32, int* __restrict__ flags) {
    __shared__ int cnt[256];
    int t = threadIdx.x;
    unsigned int w = xw[t];
    int e = (int)((w >> 23) & 0xffu);
    cnt[t] = (e >= 110 && e <= 135) ? 1 : 0;
    __syncthreads();
    for (int off = 128; off > 0; off >>= 1) {
        if (t < off) cnt[t] += cnt[t + off];
        __syncthreads();
    }
    if (t == 0) {
        flags[0] = (cnt[0] >= 128) ? 1 : 0;
        int i64 = (ei32[1] == 0 && ei32[3] == 0 && ei32[5] == 0 &&
                   ei32[7] == 0 && ei32[9] == 0) ? 1 : 0;
        flags[1] = i64;
    }
}

__global__ void g4_zero(int* __restrict__ deg, int* __restrict__ cnt,
                        unsigned int* __restrict__ outw) {
    int i = blockIdx.x * 256 + threadIdx.x;
    if (i < NN) { deg[i] = 0; cnt[i] = 0; }
    if (i < SENT_WORDS) outw[i] = SENT_VAL;
}

// ---------------------------------------------------------------------------
// CSR build
// ---------------------------------------------------------------------------
__global__ void g4_hist(const int* __restrict__ ei, const int* __restrict__ flags,
                        int* __restrict__ deg) {
    int e = blockIdx.x * blockDim.x + threadIdx.x;
    if (e >= ETOT) return;
    int i64 = flags[1];
    int d;
    if (e < EE) d = i64 ? ei[2 * (EE + e)] : ei[EE + e];
    else        d = e - EE;
    atomicAdd(&deg[d], 1);
}

__global__ void g4_scan_block(const int* __restrict__ deg, int* __restrict__ tmp,
                              int* __restrict__ partial) {
    __shared__ int sh[256];
    int i = blockIdx.x * 256 + threadIdx.x;
    int v = (i < NN) ? deg[i] : 0;
    sh[threadIdx.x] = v;
    __syncthreads();
    for (int off = 1; off < 256; off <<= 1) {
        int t = (threadIdx.x >= off) ? sh[threadIdx.x - off] : 0;
        __syncthreads();
        sh[threadIdx.x] += t;
        __syncthreads();
    }
    if (i < NN) tmp[i] = sh[threadIdx.x] - v;
    if (threadIdx.x == 255) partial[blockIdx.x] = sh[255];
}

__global__ void g4_scan_partial(int* __restrict__ partial, int nb,
                                int* __restrict__ rowptrN) {
    __shared__ int sh[256];
    int v = (threadIdx.x < nb) ? partial[threadIdx.x] : 0;
    sh[threadIdx.x] = v;
    __syncthreads();
    for (int off = 1; off < 256; off <<= 1) {
        int t = (threadIdx.x >= off) ? sh[threadIdx.x - off] : 0;
        __syncthreads();
        sh[threadIdx.x] += t;
        __syncthreads();
    }
    if (threadIdx.x < nb) partial[threadIdx.x] = sh[threadIdx.x] - v;
    if (threadIdx.x == 0) *rowptrN = ETOT;
}

__global__ void g4_scan_add(const int* __restrict__ tmp, const int* __restrict__ partial,
                            int* __restrict__ rowptr) {
    int i = blockIdx.x * 256 + threadIdx.x;
    if (i < NN) rowptr[i] = tmp[i] + partial[blockIdx.x];
}

__global__ void g4_fill_csr(const int* __restrict__ ei, const int* __restrict__ flags,
                            const int* __restrict__ rowptr,
                            int* __restrict__ cnt, int* __restrict__ col) {
    int e = blockIdx.x * blockDim.x + threadIdx.x;
    if (e >= ETOT) return;
    int i64 = flags[1];
    int s, d;
    if (e < EE) {
        s = i64 ? ei[2 * e] : ei[e];
        d = i64 ? ei[2 * (EE + e)] : ei[EE + e];
    } else {
        s = e - EE; d = e - EE;
    }
    int pos = rowptr[d] + atomicAdd(&cnt[d], 1);
    col[pos] = s;
}

// ---------------------------------------------------------------------------
// Weight prep: Bt[n][k] (bf16, K zero-padded to KP) from B[k][n].
// ---------------------------------------------------------------------------
__global__ void g4_bprep(const void* __restrict__ B, const int* __restrict__ flags,
                         unsigned short* __restrict__ Bt, int K, int kshift, int Nc) {
    int i = blockIdx.x * 256 + threadIdx.x;
    int KP = 1 << kshift;
    if (i >= Nc << kshift) return;
    int n = i >> kshift;
    int k = i & (KP - 1);
    unsigned short v = 0;
    if (k < K) {
        if (flags[0]) v = g4_f2bf(((const float*)B)[(size_t)k * Nc + n]);
        else          v = ((const unsigned short*)B)[(size_t)k * Nc + n];
    }
    Bt[(size_t)n * KP + k] = v;
}

// ---------------------------------------------------------------------------
// MFMA GEMM + fused attention logits. 64x256 tile, 4 waves = 4 heads.
// ---------------------------------------------------------------------------
#define LDK 40
__global__ __launch_bounds__(256) void g4_gemm2(
    const void* __restrict__ A, int a_mode, const unsigned short* __restrict__ Bt,
    const int* __restrict__ flags, unsigned short* __restrict__ C,
    const void* __restrict__ att_src, const void* __restrict__ att_dst,
    float* __restrict__ a_srcO, float* __restrict__ a_dstO,
    int M, int K, int KP) {
    __shared__ short As[64 * LDK];
    __shared__ short Bs[256 * LDK];
    const int isf = flags[0];
    const int af  = (a_mode == 0) ? isf : 0;
    const int tid  = threadIdx.x;
    const int lane = tid & 63;
    const int wc   = tid >> 6;       // wave = head
    const int quad = lane >> 4;
    const int l15  = lane & 15;
    const int bm = blockIdx.x * 64;
    const int a_vec = (af == 0) && ((K & 31) == 0);

    g4_f32x4 acc[4][4];
    #pragma unroll
    for (int it = 0; it < 4; it++)
        #pragma unroll
        for (int jt = 0; jt < 4; jt++) {
            acc[it][jt].x = 0.f; acc[it][jt].y = 0.f;
            acc[it][jt].z = 0.f; acc[it][jt].w = 0.f;
        }

    for (int k0 = 0; k0 < KP; k0 += 32) {
        {
            int row = tid >> 2, kc = (tid & 3) * 8;
            int gm = bm + row;
            short v[8];
            if (a_vec && gm < M) {
                *(g4_bf16x8*)v = *(const g4_bf16x8*)((const short*)A + (size_t)gm * K + k0 + kc);
            } else {
                #pragma unroll
                for (int j = 0; j < 8; j++) {
                    int gk = k0 + kc + j;
                    if (gm < M && gk < K) {
                        if (af == 0) v[j] = ((const short*)A)[(size_t)gm * K + gk];
                        else         v[j] = (short)g4_f2bf(((const float*)A)[(size_t)gm * K + gk]);
                    } else v[j] = 0;
                }
            }
            *(g4_bf16x8*)&As[row * LDK + kc] = *(g4_bf16x8*)v;
        }
        {
            const unsigned short* bp = Bt + (size_t)tid * KP + k0;
            short* dst = &Bs[tid * LDK];
            *(g4_bf16x8*)(dst + 0)  = *(const g4_bf16x8*)(bp + 0);
            *(g4_bf16x8*)(dst + 8)  = *(const g4_bf16x8*)(bp + 8);
            *(g4_bf16x8*)(dst + 16) = *(const g4_bf16x8*)(bp + 16);
            *(g4_bf16x8*)(dst + 24) = *(const g4_bf16x8*)(bp + 24);
        }
        __syncthreads();
        g4_bf16x8 afr[4], bfr[4];
        #pragma unroll
        for (int it = 0; it < 4; it++)
            afr[it] = *(const g4_bf16x8*)&As[(it * 16 + l15) * LDK + quad * 8];
        #pragma unroll
        for (int jt = 0; jt < 4; jt++)
            bfr[jt] = *(const g4_bf16x8*)&Bs[(wc * 64 + jt * 16 + l15) * LDK + quad * 8];
        #pragma unroll
        for (int it = 0; it < 4; it++)
            #pragma unroll
            for (int jt = 0; jt < 4; jt++)
                acc[it][jt] = __builtin_amdgcn_mfma_f32_16x16x32_bf16(
                    afr[it], bfr[jt], acc[it][jt], 0, 0, 0);
        __syncthreads();
    }
    #pragma unroll
    for (int it = 0; it < 4; it++) {
        #pragma unroll
        for (int jt = 0; jt < 4; jt++) {
            int gn   = wc * 64 + jt * 16 + l15;
            int row0 = bm + it * 16 + quad * 4;
            #pragma unroll
            for (int r = 0; r < 4; r++) {
                int gm = row0 + r;
                if (gm < M) C[(size_t)gm * HC + gn] = g4_f2bf(acc[it][jt][r]);
            }
        }
    }
    float asv[4], adv[4];
    #pragma unroll
    for (int jt = 0; jt < 4; jt++) {
        asv[jt] = g4_ld(att_src, wc * 64 + jt * 16 + l15, isf);
        adv[jt] = g4_ld(att_dst, wc * 64 + jt * 16 + l15, isf);
    }
    #pragma unroll
    for (int it = 0; it < 4; it++) {
        #pragma unroll
        for (int r = 0; r < 4; r++) {
            float ps = 0.f, pd = 0.f;
            #pragma unroll
            for (int jt = 0; jt < 4; jt++) {
                ps += acc[it][jt][r] * asv[jt];
                pd += acc[it][jt][r] * adv[jt];
            }
            #pragma unroll
            for (int off = 1; off < 16; off <<= 1) {
                ps += __shfl_xor(ps, off);
                pd += __shfl_xor(pd, off);
            }
            if (l15 == 0) {
                int gm = bm + it * 16 + quad * 4 + r;
                if (gm < M) {
                    a_srcO[gm * 4 + wc] = ps;
                    a_dstO[gm * 4 + wc] = pd;
                }
            }
        }
    }
}

// ---------------------------------------------------------------------------
// Fused softmax+gather, no alpha materialization. Wave per dst.
// Phase 1: per-head max over edges (lane-strided, a_src L2-resident).
// Phase 2: 16-edge chunks. Lane 4e+q computes exp for (edge e, head q)
//          inline; denominator accumulated in-register; lane also acts as
//          channel owner (ch = lane*4, head hd = lane>>4) for 4-wide
//          pipelined h-loads. Epilogue: *1/denom, +bias, ELU, bf16 store.
// ---------------------------------------------------------------------------
__global__ __launch_bounds__(256) void g4_gatherf(
    const unsigned short* __restrict__ h,
    const float* __restrict__ a_src, const float* __restrict__ a_dst,
    const int* __restrict__ rowptr, const int* __restrict__ col,
    const void* __restrict__ bias, const int* __restrict__ flags,
    unsigned short* __restrict__ xout) {
    int d    = (blockIdx.x * blockDim.x + threadIdx.x) >> 6;
    int lane = threadIdx.x & 63;
    if (d >= NN) return;
    d = __builtin_amdgcn_readfirstlane(d);
    const int isf = flags[0];
    const int hd  = lane >> 4;        // head for channel role
    const int q   = lane & 3;         // head for exp role
    const int eloc = lane >> 2;       // edge slot for exp role (0..15)
    const int l15 = lane & 15;
    const int start = __builtin_amdgcn_readfirstlane(rowptr[d]);
    const int end   = __builtin_amdgcn_readfirstlane(rowptr[d + 1]);

    // ---- phase 1: per-head max of leaky-relu logits
    g4_f32x4 ad4 = *(const g4_f32x4*)(a_dst + 4 * (size_t)d);
    float mx[4] = {-1e30f, -1e30f, -1e30f, -1e30f};
    for (int i = start + lane; i < end; i += 64) {
        int s = col[i];
        g4_f32x4 as = *(const g4_f32x4*)(a_src + 4 * (size_t)s);
        #pragma unroll
        for (int hh = 0; hh < 4; hh++) {
            float e = as[hh] + ad4[hh];
            e = (e > 0.f) ? e : NEG_SLOPE * e;
            mx[hh] = fmaxf(mx[hh], e);
        }
    }
    for (int off = 32; off > 0; off >>= 1)
        #pragma unroll
        for (int hh = 0; hh < 4; hh++) mx[hh] = fmaxf(mx[hh], __shfl_xor(mx[hh], off));
    // scalars for this lane's exp role (head q) and the a_dst term
    float mxq = (q < 2) ? ((q == 0) ? mx[0] : mx[1]) : ((q == 2) ? mx[2] : mx[3]);
    float adq = (q < 2) ? ((q == 0) ? ad4.x : ad4.y) : ((q == 2) ? ad4.z : ad4.w);

    // ---- phase 2: gather + inline exp + denom
    float a0 = 0.f, a1 = 0.f, a2 = 0.f, a3 = 0.f;
    float sm = 0.f;                    // partial denom for head q
    const size_t ch = (size_t)(lane << 2);
    for (int base = start; base < end; base += 16) {
        int m = end - base;
        if (m > 16) m = 16;
        int cv = col[base + l15];              // edges base..base+15 (x4 dup)
        int sE = __shfl(cv, eloc);             // this lane's exp-role src
        float av = 0.f;
        if (eloc < m) {
            float e = a_src[4 * (size_t)sE + q] + adq;
            e = (e > 0.f) ? e : NEG_SLOPE * e;
            av = __expf(e - mxq);
            sm += av;
        }
        int j = 0;
        for (; j + 4 <= m; j += 4) {
            int s0 = __shfl(cv, j);
            int s1 = __shfl(cv, j + 1);
            int s2 = __shfl(cv, j + 2);
            int s3 = __shfl(cv, j + 3);
            float w0 = __shfl(av, 4 * j + hd);
            float w1 = __shfl(av, 4 * j + 4 + hd);
            float w2 = __shfl(av, 4 * j + 8 + hd);
            float w3 = __shfl(av, 4 * j + 12 + hd);
            uint2 h0 = *(const uint2*)(h + (((size_t)s0) << 8) + ch);
            uint2 h1 = *(const uint2*)(h + (((size_t)s1) << 8) + ch);
            uint2 h2 = *(const uint2*)(h + (((size_t)s2) << 8) + ch);
            uint2 h3 = *(const uint2*)(h + (((size_t)s3) << 8) + ch);
            a0 = fmaf(__uint_as_float(h0.x << 16),         w0, a0);
            a1 = fmaf(__uint_as_float(h0.x & 0xffff0000u), w0, a1);
            a2 = fmaf(__uint_as_float(h0.y << 16),         w0, a2);
            a3 = fmaf(__uint_as_float(h0.y & 0xffff0000u), w0, a3);
            a0 = fmaf(__uint_as_float(h1.x << 16),         w1, a0);
            a1 = fmaf(__uint_as_float(h1.x & 0xffff0000u), w1, a1);
            a2 = fmaf(__uint_as_float(h1.y << 16),         w1, a2);
            a3 = fmaf(__uint_as_float(h1.y & 0xffff0000u), w1, a3);
            a0 = fmaf(__uint_as_float(h2.x << 16),         w2, a0);
            a1 = fmaf(__uint_as_float(h2.x & 0xffff0000u), w2, a1);
            a2 = fmaf(__uint_as_float(h2.y << 16),         w2, a2);
            a3 = fmaf(__uint_as_float(h2.y & 0xffff0000u), w2, a3);
            a0 = fmaf(__uint_as_float(h3.x << 16),         w3, a0);
            a1 = fmaf(__uint_as_float(h3.x & 0xffff0000u), w3, a1);
            a2 = fmaf(__uint_as_float(h3.y << 16),         w3, a2);
            a3 = fmaf(__uint_as_float(h3.y & 0xffff0000u), w3, a3);
        }
        for (; j < m; j++) {
            int s = __shfl(cv, j);
            float w = __shfl(av, 4 * j + hd);
            uint2 hv = *(const uint2*)(h + (((size_t)s) << 8) + ch);
            a0 = fmaf(__uint_as_float(hv.x << 16),         w, a0);
            a1 = fmaf(__uint_as_float(hv.x & 0xffff0000u), w, a1);
            a2 = fmaf(__uint_as_float(hv.y << 16),         w, a2);
            a3 = fmaf(__uint_as_float(hv.y & 0xffff0000u), w, a3);
        }
    }
    // denom reduce over lanes with same q (xor strides 4..32 preserve q)
    for (int off = 4; off < 64; off <<= 1) sm += __shfl_xor(sm, off);
    // this lane (channel role, head hd) needs denom of head hd: lane hd holds q==hd
    float inv = 1.f / __shfl(sm, hd);
    float acc[4] = {a0 * inv, a1 * inv, a2 * inv, a3 * inv};
    unsigned short ov[4];
    #pragma unroll
    for (int j = 0; j < 4; j++) {
        float v = acc[j] + g4_ld(bias, (lane << 2) + j, isf);
        v = (v > 0.f) ? v : (__expf(v) - 1.f);
        ov[j] = g4_f2bf(v);
    }
    uint2 pack;
    pack.x = (unsigned int)ov[0] | ((unsigned int)ov[1] << 16);
    pack.y = (unsigned int)ov[2] | ((unsigned int)ov[3] << 16);
    *(uint2*)(xout + ((size_t)d << 8) + (lane << 2)) = pack;
}

// ---------------------------------------------------------------------------
// Fused MLP head
// ---------------------------------------------------------------------------
__global__ __launch_bounds__(256) void g4_head2(
    const unsigned short* __restrict__ x, const void* __restrict__ w1,
    const void* __restrict__ b1, const void* __restrict__ w2,
    const void* __restrict__ b2, const int* __restrict__ flags,
    void* __restrict__ outp) {
    __shared__ float As[64][17];
    __shared__ float Bs[16][64];
    __shared__ float red[64][17];
    const int isf = flags[0];
    const int tid = threadIdx.x;
    const int bm  = blockIdx.x * 64;
    const int tx  = tid & 15;
    const int ty  = tid >> 4;
    float acc[4][4] = {};
    for (int k0 = 0; k0 < HC; k0 += 16) {
        for (int i = tid; i < 64 * 16; i += 256) {
            int m = i >> 4, kk = i & 15;
            int gm = bm + m;
            float v = 0.f;
            if (gm < NN) v = g4_bf2f(x[(size_t)gm * HC + k0 + kk]);
            As[m][kk] = v;
        }
        for (int i = tid; i < 16 * 64; i += 256) {
            int kk = i >> 6, n = i & 63;
            Bs[kk][n] = g4_ld(w1, (size_t)(k0 + kk) * 64 + n, isf);
        }
        __syncthreads();
        #pragma unroll
        for (int kk = 0; kk < 16; ++kk) {
            float a[4], b[4];
            #pragma unroll
            for (int i = 0; i < 4; i++) a[i] = As[ty * 4 + i][kk];
            #pragma unroll
            for (int j = 0; j < 4; j++) b[j] = Bs[kk][tx * 4 + j];
            #pragma unroll
            for (int i = 0; i < 4; i++)
                #pragma unroll
                for (int j = 0; j < 4; j++) acc[i][j] += a[i] * b[j];
        }
        __syncthreads();
    }
    float b1v[4], w2v[4];
    #pragma unroll
    for (int j = 0; j < 4; j++) {
        b1v[j] = g4_ld(b1, tx * 4 + j, isf);
        w2v[j] = g4_ld(w2, tx * 4 + j, isf);
    }
    #pragma unroll
    for (int i = 0; i < 4; i++) {
        float s = 0.f;
        #pragma unroll
        for (int j = 0; j < 4; j++) {
            float v = acc[i][j] + b1v[j];
            v = fmaxf(v, 0.f);
            s += v * w2v[j];
        }
        red[ty * 4 + i][tx] = s;
    }
    __syncthreads();
    if (tid < 64) {
        float s = 0.f;
        #pragma unroll
        for (int g = 0; g < 16; g++) s += red[tid][g];
        int gm = bm + tid;
        if (gm < NN) {
            float r = s + g4_ld(b2, 0, isf);
            if (isf) ((float*)outp)[gm] = r;
            else     ((unsigned short*)outp)[gm] = g4_f2bf(r);
        }
    }
}

// ---------------------------------------------------------------------------
extern "C" __attribute__((visibility("default")))
void kernel_launch(void* const* d_in, const int* in_sizes, int n_in,
                   void* d_out, int out_size, void* d_ws, size_t ws_size,
                   hipStream_t stream) {
    const void* x_in = d_in[0];
    const int*  ei   = (const int*)d_in[1];
    const void* W[3]    = {d_in[2], d_in[6], d_in[10]};
    const void* ASRC[3] = {d_in[3], d_in[7], d_in[11]};
    const void* ADST[3] = {d_in[4], d_in[8], d_in[12]};
    const void* BIAS[3] = {d_in[5], d_in[9], d_in[13]};
    const void* hw1 = d_in[14];
    const void* hb1 = d_in[15];
    const void* hw2 = d_in[16];
    const void* hb2 = d_in[17];

    char* base = (char*)d_ws;
    size_t woff = 0;
#define G4_TAKE(name, type, count) \
    type* name = (type*)(base + woff); \
    woff += (((size_t)(count)) * sizeof(type) + 255) & ~(size_t)255;
    G4_TAKE(flags,   int, 8)
    G4_TAKE(deg,     int, NN)
    G4_TAKE(cnt,     int, NN)
    G4_TAKE(tmp,     int, NN)
    G4_TAKE(partial, int, 256)
    G4_TAKE(rowptr,  int, NN + 1)
    G4_TAKE(col,     int, ETOT + 16)                 // +16 pad (chunked reads)
    G4_TAKE(asr,     float, (size_t)NN * 4)
    G4_TAKE(adsb,    float, (size_t)NN * 4)
    G4_TAKE(Bt,      unsigned short, (size_t)HC * HC)
    G4_TAKE(hbuf,    unsigned short, (size_t)NN * HC)
    G4_TAKE(xbuf,    unsigned short, (size_t)NN * HC)
#undef G4_TAKE

    const int SCAN_BLOCKS = (NN + 255) / 256;          // 196
    const int EDGE_BLOCKS = (ETOT + 255) / 256;        // 3321
    const int WAVE_BLOCKS = (NN + 3) / 4;              // 12500
    const int TILE_BLOCKS = (NN + 63) / 64;            // 782

    g4_detect<<<1, 256, 0, stream>>>((const unsigned int*)x_in, ei, flags);
    g4_zero<<<SCAN_BLOCKS, 256, 0, stream>>>(deg, cnt, (unsigned int*)d_out);

    g4_hist<<<EDGE_BLOCKS, 256, 0, stream>>>(ei, flags, deg);
    g4_scan_block<<<SCAN_BLOCKS, 256, 0, stream>>>(deg, tmp, partial);
    g4_scan_partial<<<1, 256, 0, stream>>>(partial, SCAN_BLOCKS, rowptr + NN);
    g4_scan_add<<<SCAN_BLOCKS, 256, 0, stream>>>(tmp, partial, rowptr);
    g4_fill_csr<<<EDGE_BLOCKS, 256, 0, stream>>>(ei, flags, rowptr, cnt, col);

    for (int l = 0; l < 3; l++) {
        int K      = (l == 0) ? 61 : HC;
        int kshift = (l == 0) ? 6  : 8;     // KP = 64 or 256
        int KP     = 1 << kshift;
        int pb     = ((HC << kshift) + 255) / 256;
        g4_bprep<<<pb, 256, 0, stream>>>(W[l], flags, Bt, K, kshift, HC);
        if (l == 0) {
            g4_gemm2<<<TILE_BLOCKS, 256, 0, stream>>>(x_in, 0, Bt, flags, hbuf,
                ASRC[l], ADST[l], asr, adsb, NN, K, KP);
        } else {
            g4_gemm2<<<TILE_BLOCKS, 256, 0, stream>>>(xbuf, 1, Bt, flags, hbuf,
                ASRC[l], ADST[l], asr, adsb, NN, K, KP);
        }
        g4_gatherf<<<WAVE_BLOCKS, 256, 0, stream>>>(hbuf, asr, adsb, rowptr, col,
                                                    BIAS[l], flags, xbuf);
    }
    g4_head2<<<TILE_BLOCKS, 256, 0, stream>>>(xbuf, hw1, hb1, hw2, hb2, flags, d_out);
}